// Round 9
// baseline (769.682 us; speedup 1.0000x reference)
//
#include <hip/hip_runtime.h>
#include <hip/hip_bf16.h>

typedef float f32x4 __attribute__((ext_vector_type(4)));
typedef unsigned short u16x8 __attribute__((ext_vector_type(8)));

static __device__ __forceinline__ void mfma16(f32x4& c, const u16x8& a, const u16x8& b) {
    asm("v_mfma_f32_16x16x32_bf16 %0, %1, %2, %0" : "+v"(c) : "v"(a), "v"(b));
}

static __device__ __forceinline__ unsigned short f2bf(float f) {
    __hip_bfloat16 h = __float2bfloat16(f);
    return *reinterpret_cast<unsigned short*>(&h);
}

static __device__ __forceinline__ float bflo(unsigned int v) { return __uint_as_float(v << 16); }
static __device__ __forceinline__ float bfhi(unsigned int v) { return __uint_as_float(v & 0xffff0000u); }

// ---------------- small prep kernels ----------------

__global__ __launch_bounds__(1024) void k_dis_blocksum(float* deg, const int* __restrict__ cnt,
                                                       int* bsum, int N) {
    __shared__ int sd[1024];
    int i = blockIdx.x * 1024 + threadIdx.x;
    if (i < N) {
        float d = deg[i];
        deg[i] = (d > 0.f) ? rsqrtf(d) : 0.f;
    }
    sd[threadIdx.x] = (i < N) ? cnt[i] : 0;
    __syncthreads();
    for (int s = 512; s > 0; s >>= 1) {
        if (threadIdx.x < s) sd[threadIdx.x] += sd[threadIdx.x + s];
        __syncthreads();
    }
    if (threadIdx.x == 0) bsum[blockIdx.x] = sd[0];
}

__global__ __launch_bounds__(128) void k_scan_bsum(int* bsum, int nb) {
    __shared__ int sd[128];
    int t = threadIdx.x;
    int v = (t < nb) ? bsum[t] : 0;
    sd[t] = v;
    __syncthreads();
    for (int d = 1; d < 128; d <<= 1) {
        int x = (t >= d) ? sd[t - d] : 0;
        __syncthreads();
        sd[t] += x;
        __syncthreads();
    }
    if (t < nb) bsum[t] = sd[t] - v;  // exclusive block offsets
}

__global__ __launch_bounds__(1024) void k_scan(const int* __restrict__ cnt, const int* __restrict__ bsum,
                                               int* rowp, int N) {
    __shared__ int sd[1024];
    int i = blockIdx.x * 1024 + threadIdx.x;
    int v = (i < N) ? cnt[i] : 0;
    sd[threadIdx.x] = v;
    __syncthreads();
    for (int d = 1; d < 1024; d <<= 1) {
        int x = (threadIdx.x >= d) ? sd[threadIdx.x - d] : 0;
        __syncthreads();
        sd[threadIdx.x] += x;
        __syncthreads();
    }
    if (i < N) rowp[i] = sd[threadIdx.x] - v + bsum[blockIdx.x];
}

// atomic-free CSR fill: pos = rowp[dst] + rank (u8, captured during mega's counting atomics)
__global__ __launch_bounds__(256) void k_build_csr(const int* __restrict__ src, const int* __restrict__ dst,
                                                   const float* __restrict__ ew, const float* __restrict__ dis,
                                                   const int* __restrict__ rowp,
                                                   const unsigned char* __restrict__ rank,
                                                   int2* __restrict__ pack, int E) {
    int base = blockIdx.x * 512 + threadIdx.x;
#pragma unroll
    for (int u = 0; u < 2; u++) {
        int e = base + u * 256;
        if (e < E) {
            int s = src[e], d = dst[e];
            float w = (s == d) ? 0.f : ew[e];
            float wh = -dis[s] * w * dis[d];
            int pos = rowp[d] + (int)rank[e];
            int2 p;
            p.x = s;
            p.y = __float_as_int(wh);
            pack[pos] = p;
        }
    }
}

// ---------------- weight prep ----------------

// AT[sel][n][kk] = A_sel[kk][n] (transposed, bf16), A0=W0-W2, A1=W1-3W3, A2=2W2, A3=4W3
__global__ __launch_bounds__(256) void k_combine(const float* __restrict__ W, unsigned short* __restrict__ AT,
                                                 int D, int KPAD) {
    int i = blockIdx.x * 256 + threadIdx.x;
    int tot = 4 * 128 * KPAD;
    if (i >= tot) return;
    int sel = i / (128 * KPAD);
    int rem = i - sel * 128 * KPAD;
    int n = rem / KPAD;
    int kk = rem - n * KPAD;
    float v = 0.f;
    if (kk < D) {
        if (sel == 0)      v = W[(0 * D + kk) * 128 + n] - W[(2 * D + kk) * 128 + n];
        else if (sel == 1) v = W[(1 * D + kk) * 128 + n] - 3.f * W[(3 * D + kk) * 128 + n];
        else if (sel == 2) v = 2.f * W[(2 * D + kk) * 128 + n];
        else               v = 4.f * W[(3 * D + kk) * 128 + n];
    }
    AT[i] = f2bf(v);
}

__global__ __launch_bounds__(256) void k_headsT(const float* __restrict__ Wmu, const float* __restrict__ Wlv,
                                                unsigned short* __restrict__ AT) {
    int i = blockIdx.x * 256 + threadIdx.x;
    if (i >= 128 * 128) return;
    int n = i >> 7, kk = i & 127;
    float v = (n < 64) ? Wmu[kk * 64 + n] : Wlv[kk * 64 + (n - 64)];
    AT[i] = f2bf(v);
}

// ---------------- reg-B pair GEMM body (mega layer-0): BM=64, BN=128, 2 weights/block ----------------

template <int KPAD>
static __device__ __forceinline__ void gemm_pair_regB(const float* __restrict__ x,
                                                      const float* __restrict__ pe,
                                                      const unsigned short* __restrict__ Bta,
                                                      const unsigned short* __restrict__ Btb,
                                                      unsigned short* __restrict__ outA,
                                                      unsigned short* __restrict__ outB,
                                                      int N, int bx, unsigned short* As) {
    constexpr int LP = KPAD + 8;
    const int tid = threadIdx.x;
    const int row0 = bx * 64;

    {   // stage A tile (64 x KPAD) = concat(x, pe, pad) -> bf16
        constexpr int TOT = 64 * KPAD;
        for (int c = tid * 8; c < TOT; c += 256 * 8) {
            int r = c / KPAD;
            int k = c - r * KPAD;
            int gr = row0 + r;
            if (gr > N - 1) gr = N - 1;
            u16x8 v;
            if (k < 128) {
                float4 f0 = *reinterpret_cast<const float4*>(&x[(size_t)gr * 128 + k]);
                float4 f1 = *reinterpret_cast<const float4*>(&x[(size_t)gr * 128 + k + 4]);
                v[0] = f2bf(f0.x); v[1] = f2bf(f0.y); v[2] = f2bf(f0.z); v[3] = f2bf(f0.w);
                v[4] = f2bf(f1.x); v[5] = f2bf(f1.y); v[6] = f2bf(f1.z); v[7] = f2bf(f1.w);
            } else if (k < 144) {
                float4 f0 = *reinterpret_cast<const float4*>(&pe[(size_t)gr * 16 + (k - 128)]);
                float4 f1 = *reinterpret_cast<const float4*>(&pe[(size_t)gr * 16 + (k - 124)]);
                v[0] = f2bf(f0.x); v[1] = f2bf(f0.y); v[2] = f2bf(f0.z); v[3] = f2bf(f0.w);
                v[4] = f2bf(f1.x); v[5] = f2bf(f1.y); v[6] = f2bf(f1.z); v[7] = f2bf(f1.w);
            } else {
                v = (u16x8){0, 0, 0, 0, 0, 0, 0, 0};
            }
            *reinterpret_cast<u16x8*>(&As[r * LP + k]) = v;
        }
    }
    __syncthreads();

    const int wave = tid >> 6, lane = tid & 63;
    const int wm = wave & 1, ww = wave >> 1;
    const int lr = lane & 15, lg = lane >> 4;
    const unsigned short* Bw = ww ? Btb : Bta;

    f32x4 acc[2][8];
#pragma unroll
    for (int i = 0; i < 2; i++)
#pragma unroll
        for (int j = 0; j < 8; j++) acc[i][j] = (f32x4){0.f, 0.f, 0.f, 0.f};

    asm volatile("s_nop 7"
                 : "+v"(acc[0][0]), "+v"(acc[0][4]), "+v"(acc[1][0]), "+v"(acc[1][4]));

    constexpr int KS = KPAD / 32;
#pragma unroll
    for (int ks = 0; ks < KS; ks++) {
        u16x8 a0 = *reinterpret_cast<const u16x8*>(&As[(wm * 32 + lr) * LP + ks * 32 + lg * 8]);
        u16x8 a1 = *reinterpret_cast<const u16x8*>(&As[(wm * 32 + 16 + lr) * LP + ks * 32 + lg * 8]);
#pragma unroll
        for (int g = 0; g < 2; g++) {
            u16x8 b[4];
#pragma unroll
            for (int j = 0; j < 4; j++)
                b[j] = *reinterpret_cast<const u16x8*>(&Bw[(size_t)((g * 4 + j) * 16 + lr) * KPAD + ks * 32 + lg * 8]);
#pragma unroll
            for (int j = 0; j < 4; j++) {
                mfma16(acc[0][g * 4 + j], a0, b[j]);
                mfma16(acc[1][g * 4 + j], a1, b[j]);
            }
        }
    }

    asm volatile("s_nop 7\n\ts_nop 7\n\ts_nop 7"
                 : "+v"(acc[0][0]), "+v"(acc[0][4]), "+v"(acc[1][0]), "+v"(acc[1][4]));

    unsigned short* outp = ww ? outB : outA;
#pragma unroll
    for (int fm = 0; fm < 2; fm++)
#pragma unroll
        for (int fn = 0; fn < 8; fn++)
#pragma unroll
            for (int i = 0; i < 4; i++) {
                int r = row0 + wm * 32 + fm * 16 + lg * 4 + i;
                if (r < N) outp[(size_t)r * 128 + fn * 16 + lr] = f2bf(acc[fm][fn][i]);
            }
}

// ---------------- K1 mega: {layer-0 pair-GEMM tile, fused concat} then {deg FF + cnt/rank atomics} ----------------

__global__ __launch_bounds__(256, 4) void k_mega(const int* __restrict__ src, const int* __restrict__ dst,
                                                 const float* __restrict__ ew,
                                                 float* deg, int* cnt, unsigned char* __restrict__ rank,
                                                 const float* __restrict__ x, const float* __restrict__ pe,
                                                 const unsigned short* __restrict__ AT0,
                                                 unsigned short* __restrict__ oZ3, unsigned short* __restrict__ oZ2,
                                                 unsigned short* __restrict__ oZ1, unsigned short* __restrict__ oZ0,
                                                 int N, int E, int EPC) {
    __shared__ __align__(16) unsigned short As[64 * 168];
    const int bid = blockIdx.x;

    {
        int P = bid & 1;
        int bx = bid >> 1;
        const unsigned short* Bta = AT0 + (size_t)(3 - 2 * P) * 128 * 160;
        const unsigned short* Btb = AT0 + (size_t)(2 - 2 * P) * 128 * 160;
        unsigned short* outA = (P == 0) ? oZ3 : oZ1;
        unsigned short* outB = (P == 0) ? oZ2 : oZ0;
        gemm_pair_regB<160>(x, pe, Bta, Btb, outA, outB, N, bx, As);
    }

    {
        int e0 = bid * EPC;
        int e1 = e0 + EPC;
        if (e1 > E) e1 = E;
        for (int e = e0 + threadIdx.x; e < e1; e += 256) {
            int s = src[e], d = dst[e];
            float w = (s == d) ? 0.f : ew[e];
            atomicAdd(&deg[s], w);
            rank[e] = (unsigned char)atomicAdd(&cnt[d], 1);
        }
    }
}

// ---------------- fused layer-1 GEMM (K=512 powers form) + heads ----------------
// h2 = relu([h1|U1|U2|U3] @ [A0;A1;A2;A3] + b1)  (h2 kept in LDS), then [mu|lv] = h2 @ ATH^T + bias.

__global__ __launch_bounds__(256, 4) void k_gemm_l1_heads(const unsigned short* __restrict__ h1,
                                                          const unsigned short* __restrict__ U1,
                                                          const unsigned short* __restrict__ U2,
                                                          const unsigned short* __restrict__ U3,
                                                          const unsigned short* __restrict__ AT1,
                                                          const unsigned short* __restrict__ ATH,
                                                          const float* __restrict__ b1,
                                                          const float* __restrict__ bmu,
                                                          const float* __restrict__ blv,
                                                          float* __restrict__ out, int N) {
    constexpr int LP = 136;
    __shared__ __align__(16) unsigned short As[64 * LP];
    const int tid = threadIdx.x;
    const int row0 = blockIdx.x * 64;
    const int wave = tid >> 6, lane = tid & 63;
    const int wm = wave & 1, wn = wave >> 1;
    const int lr = lane & 15, lg = lane >> 4;

    f32x4 acc[2][4];
#pragma unroll
    for (int i = 0; i < 2; i++)
#pragma unroll
        for (int j = 0; j < 4; j++) acc[i][j] = (f32x4){0.f, 0.f, 0.f, 0.f};

#pragma unroll 4
    for (int seg = 0; seg < 4; seg++) {
        const unsigned short* sp = (seg == 0) ? h1 : (seg == 1) ? U1 : (seg == 2) ? U2 : U3;
        // stage A tile (64 x 128)
        for (int c = tid * 8; c < 64 * 128; c += 256 * 8) {
            int r = c >> 7;
            int k = c & 127;
            int gr = row0 + r;
            if (gr > N - 1) gr = N - 1;
            u16x8 v = *reinterpret_cast<const u16x8*>(&sp[(size_t)gr * 128 + k]);
            *reinterpret_cast<u16x8*>(&As[r * LP + k]) = v;
        }
        __syncthreads();
        const unsigned short* Bseg = AT1 + (size_t)seg * 128 * 128;
#pragma unroll
        for (int ks = 0; ks < 4; ks++) {
            u16x8 a0 = *reinterpret_cast<const u16x8*>(&As[(wm * 32 + lr) * LP + ks * 32 + lg * 8]);
            u16x8 a1 = *reinterpret_cast<const u16x8*>(&As[(wm * 32 + 16 + lr) * LP + ks * 32 + lg * 8]);
            u16x8 b[4];
#pragma unroll
            for (int j = 0; j < 4; j++)
                b[j] = *reinterpret_cast<const u16x8*>(&Bseg[(size_t)((wn * 64 + j * 16 + lr)) * 128 + ks * 32 + lg * 8]);
#pragma unroll
            for (int j = 0; j < 4; j++) {
                mfma16(acc[0][j], a0, b[j]);
                mfma16(acc[1][j], a1, b[j]);
            }
        }
        __syncthreads();  // protect As before next stage overwrites
    }

    // fence MFMA->VALU, then h2 = relu(acc + b1) -> LDS (bf16)
    asm volatile("s_nop 7\n\ts_nop 7\n\ts_nop 7"
                 : "+v"(acc[0][0]), "+v"(acc[0][1]), "+v"(acc[0][2]), "+v"(acc[0][3]),
                   "+v"(acc[1][0]), "+v"(acc[1][1]), "+v"(acc[1][2]), "+v"(acc[1][3]));

#pragma unroll
    for (int fm = 0; fm < 2; fm++)
#pragma unroll
        for (int fn = 0; fn < 4; fn++)
#pragma unroll
            for (int i = 0; i < 4; i++) {
                int rl = wm * 32 + fm * 16 + lg * 4 + i;
                int c = wn * 64 + fn * 16 + lr;
                float v = fmaxf(acc[fm][fn][i] + b1[c], 0.f);
                As[rl * LP + c] = f2bf(v);
            }
    __syncthreads();

    // heads: [mu|lv] = h2(LDS) @ ATH^T, K=128
    f32x4 acc2[2][4];
#pragma unroll
    for (int i = 0; i < 2; i++)
#pragma unroll
        for (int j = 0; j < 4; j++) acc2[i][j] = (f32x4){0.f, 0.f, 0.f, 0.f};

    asm volatile("s_nop 7"
                 : "+v"(acc2[0][0]), "+v"(acc2[0][1]), "+v"(acc2[1][0]), "+v"(acc2[1][1]));

#pragma unroll
    for (int ks = 0; ks < 4; ks++) {
        u16x8 a0 = *reinterpret_cast<const u16x8*>(&As[(wm * 32 + lr) * LP + ks * 32 + lg * 8]);
        u16x8 a1 = *reinterpret_cast<const u16x8*>(&As[(wm * 32 + 16 + lr) * LP + ks * 32 + lg * 8]);
        u16x8 b[4];
#pragma unroll
        for (int j = 0; j < 4; j++)
            b[j] = *reinterpret_cast<const u16x8*>(&ATH[(size_t)(wn * 64 + j * 16 + lr) * 128 + ks * 32 + lg * 8]);
#pragma unroll
        for (int j = 0; j < 4; j++) {
            mfma16(acc2[0][j], a0, b[j]);
            mfma16(acc2[1][j], a1, b[j]);
        }
    }

    asm volatile("s_nop 7\n\ts_nop 7\n\ts_nop 7"
                 : "+v"(acc2[0][0]), "+v"(acc2[0][1]), "+v"(acc2[1][0]), "+v"(acc2[1][1]));

#pragma unroll
    for (int fm = 0; fm < 2; fm++)
#pragma unroll
        for (int fn = 0; fn < 4; fn++)
#pragma unroll
            for (int i = 0; i < 4; i++) {
                int r = row0 + wm * 32 + fm * 16 + lg * 4 + i;
                if (r < N) {
                    int c = wn * 64 + fn * 16 + lr;
                    if (c < 64) out[(size_t)r * 64 + c] = acc2[fm][fn][i] + bmu[c];
                    else out[(size_t)N * 64 + (size_t)r * 64 + (c - 64)] = acc2[fm][fn][i] + blv[c - 64];
                }
            }
}

// ---------------- sparse prop v4: 2 nodes per wave, quarter-wave row coverage ----------------
// Per node: 4 groups of 16 lanes over CSR slots (stride 4), lane loads uint4 (16B) -> 16 lanes = 256B row.
// Two nodes' chains interleave in one loop -> >=2 independent gathers in flight regardless of degree.

template <int MODE>  // 0: z + P t ; 1: relu(z + P t + bias) ; 2: pure P t
__global__ __launch_bounds__(256) void k_prop(const uint4* __restrict__ tin4,
                                              const uint4* __restrict__ z4,
                                              uint4* __restrict__ tout4,
                                              const float* __restrict__ bias,
                                              const int* __restrict__ rowp,
                                              const long long* __restrict__ pack,
                                              int N, int E) {
    int wave = threadIdx.x >> 6, lane = threadIdx.x & 63;
    int n0 = blockIdx.x * 8 + wave * 2;
    if (n0 >= N) return;
    int n1 = n0 + 1;
    const int grp = lane >> 4, li = lane & 15;
    int beg0 = rowp[n0];
    int end0 = (n0 == N - 1) ? E : rowp[n0 + 1];
    int beg1 = 0, end1 = 0;
    if (n1 < N) {
        beg1 = rowp[n1];
        end1 = (n1 == N - 1) ? E : rowp[n1 + 1];
    }
    float s0 = 0.f, s1 = 0.f, s2 = 0.f, s3 = 0.f, s4 = 0.f, s5 = 0.f, s6 = 0.f, s7 = 0.f;
    float t0 = 0.f, t1 = 0.f, t2 = 0.f, t3 = 0.f, t4 = 0.f, t5 = 0.f, t6 = 0.f, t7 = 0.f;
    int e0 = beg0 + grp, e1 = beg1 + grp;
    while (e0 < end0 || e1 < end1) {
        bool p0 = e0 < end0, p1 = e1 < end1;
        long long qa = 0, qb = 0;
        uint4 va, vb;
        if (p0) qa = __builtin_nontemporal_load(pack + e0);
        if (p1) qb = __builtin_nontemporal_load(pack + e1);
        if (p0) va = tin4[(size_t)(unsigned int)qa * 16 + li];
        if (p1) vb = tin4[(size_t)(unsigned int)qb * 16 + li];
        if (p0) {
            float wa = __uint_as_float((unsigned int)((unsigned long long)qa >> 32));
            s0 = fmaf(wa, bflo(va.x), s0); s1 = fmaf(wa, bfhi(va.x), s1);
            s2 = fmaf(wa, bflo(va.y), s2); s3 = fmaf(wa, bfhi(va.y), s3);
            s4 = fmaf(wa, bflo(va.z), s4); s5 = fmaf(wa, bfhi(va.z), s5);
            s6 = fmaf(wa, bflo(va.w), s6); s7 = fmaf(wa, bfhi(va.w), s7);
        }
        if (p1) {
            float wb = __uint_as_float((unsigned int)((unsigned long long)qb >> 32));
            t0 = fmaf(wb, bflo(vb.x), t0); t1 = fmaf(wb, bfhi(vb.x), t1);
            t2 = fmaf(wb, bflo(vb.y), t2); t3 = fmaf(wb, bfhi(vb.y), t3);
            t4 = fmaf(wb, bflo(vb.z), t4); t5 = fmaf(wb, bfhi(vb.z), t5);
            t6 = fmaf(wb, bflo(vb.w), t6); t7 = fmaf(wb, bfhi(vb.w), t7);
        }
        e0 += 4;
        e1 += 4;
    }
    // reduce across the 4 groups
    s0 += __shfl_xor(s0, 16); s1 += __shfl_xor(s1, 16); s2 += __shfl_xor(s2, 16); s3 += __shfl_xor(s3, 16);
    s4 += __shfl_xor(s4, 16); s5 += __shfl_xor(s5, 16); s6 += __shfl_xor(s6, 16); s7 += __shfl_xor(s7, 16);
    s0 += __shfl_xor(s0, 32); s1 += __shfl_xor(s1, 32); s2 += __shfl_xor(s2, 32); s3 += __shfl_xor(s3, 32);
    s4 += __shfl_xor(s4, 32); s5 += __shfl_xor(s5, 32); s6 += __shfl_xor(s6, 32); s7 += __shfl_xor(s7, 32);
    t0 += __shfl_xor(t0, 16); t1 += __shfl_xor(t1, 16); t2 += __shfl_xor(t2, 16); t3 += __shfl_xor(t3, 16);
    t4 += __shfl_xor(t4, 16); t5 += __shfl_xor(t5, 16); t6 += __shfl_xor(t6, 16); t7 += __shfl_xor(t7, 16);
    t0 += __shfl_xor(t0, 32); t1 += __shfl_xor(t1, 32); t2 += __shfl_xor(t2, 32); t3 += __shfl_xor(t3, 32);
    t4 += __shfl_xor(t4, 32); t5 += __shfl_xor(t5, 32); t6 += __shfl_xor(t6, 32); t7 += __shfl_xor(t7, 32);

    if (lane < 16) {
        float r0 = s0, r1 = s1, r2 = s2, r3 = s3, r4 = s4, r5 = s5, r6 = s6, r7 = s7;
        if (MODE != 2) {
            uint4 zv = z4[(size_t)n0 * 16 + li];
            r0 += bflo(zv.x); r1 += bfhi(zv.x); r2 += bflo(zv.y); r3 += bfhi(zv.y);
            r4 += bflo(zv.z); r5 += bfhi(zv.z); r6 += bflo(zv.w); r7 += bfhi(zv.w);
        }
        if (MODE == 1) {
            const float* bp = bias + li * 8;
            r0 = fmaxf(r0 + bp[0], 0.f); r1 = fmaxf(r1 + bp[1], 0.f);
            r2 = fmaxf(r2 + bp[2], 0.f); r3 = fmaxf(r3 + bp[3], 0.f);
            r4 = fmaxf(r4 + bp[4], 0.f); r5 = fmaxf(r5 + bp[5], 0.f);
            r6 = fmaxf(r6 + bp[6], 0.f); r7 = fmaxf(r7 + bp[7], 0.f);
        }
        uint4 o;
        o.x = (unsigned int)f2bf(r0) | ((unsigned int)f2bf(r1) << 16);
        o.y = (unsigned int)f2bf(r2) | ((unsigned int)f2bf(r3) << 16);
        o.z = (unsigned int)f2bf(r4) | ((unsigned int)f2bf(r5) << 16);
        o.w = (unsigned int)f2bf(r6) | ((unsigned int)f2bf(r7) << 16);
        tout4[(size_t)n0 * 16 + li] = o;
        if (n1 < N) {
            float u0 = t0, u1 = t1, u2 = t2, u3 = t3, u4 = t4, u5 = t5, u6 = t6, u7 = t7;
            if (MODE != 2) {
                uint4 zv = z4[(size_t)n1 * 16 + li];
                u0 += bflo(zv.x); u1 += bfhi(zv.x); u2 += bflo(zv.y); u3 += bfhi(zv.y);
                u4 += bflo(zv.z); u5 += bfhi(zv.z); u6 += bflo(zv.w); u7 += bfhi(zv.w);
            }
            if (MODE == 1) {
                const float* bp = bias + li * 8;
                u0 = fmaxf(u0 + bp[0], 0.f); u1 = fmaxf(u1 + bp[1], 0.f);
                u2 = fmaxf(u2 + bp[2], 0.f); u3 = fmaxf(u3 + bp[3], 0.f);
                u4 = fmaxf(u4 + bp[4], 0.f); u5 = fmaxf(u5 + bp[5], 0.f);
                u6 = fmaxf(u6 + bp[6], 0.f); u7 = fmaxf(u7 + bp[7], 0.f);
            }
            uint4 o2;
            o2.x = (unsigned int)f2bf(u0) | ((unsigned int)f2bf(u1) << 16);
            o2.y = (unsigned int)f2bf(u2) | ((unsigned int)f2bf(u3) << 16);
            o2.z = (unsigned int)f2bf(u4) | ((unsigned int)f2bf(u5) << 16);
            o2.w = (unsigned int)f2bf(u6) | ((unsigned int)f2bf(u7) << 16);
            tout4[(size_t)n1 * 16 + li] = o2;
        }
    }
}

// ---------------- launch ----------------

extern "C" void kernel_launch(void* const* d_in, const int* in_sizes, int n_in,
                              void* d_out, int out_size, void* d_ws, size_t ws_size,
                              hipStream_t stream) {
    const float* x   = (const float*)d_in[0];
    const int*   ei  = (const int*)d_in[1];
    const float* pe  = (const float*)d_in[2];
    const float* ew  = (const float*)d_in[3];
    const float* W0  = (const float*)d_in[4];
    const float* b0  = (const float*)d_in[5];
    const float* W1  = (const float*)d_in[6];
    const float* b1  = (const float*)d_in[7];
    const float* Wmu = (const float*)d_in[8];
    const float* bmu = (const float*)d_in[9];
    const float* Wlv = (const float*)d_in[10];
    const float* blv = (const float*)d_in[11];

    const int N = in_sizes[0] / 128;
    const int E = in_sizes[3];
    const int* src = ei;
    const int* dst = ei + E;

    char* ws = (char*)d_ws;
    size_t off = 0;
    auto alloc = [&](size_t bytes) {
        size_t o = off;
        off += (bytes + 1023) & ~(size_t)1023;
        return o;
    };
    float* deg = (float*)(ws + alloc(4 * (size_t)N));   // becomes dis in-place
    int* cnt   = (int*)(ws + alloc(4 * (size_t)N));
    size_t zero_bytes = off;                            // memset deg+cnt
    unsigned char* rank = (unsigned char*)(ws + alloc((size_t)E));
    int* rowp  = (int*)(ws + alloc(4 * (size_t)N));
    int* bsum  = (int*)(ws + alloc(4 * 128));
    unsigned short* AT0 = (unsigned short*)(ws + alloc(2 * 4 * 128 * 160));
    unsigned short* AT1 = (unsigned short*)(ws + alloc(2 * 4 * 128 * 128));
    unsigned short* ATH = (unsigned short*)(ws + alloc(2 * 128 * 128));
    int2* pack = (int2*)(ws + alloc(8 * (size_t)E));
    unsigned int* B1 = (unsigned int*)(ws + alloc(2 * (size_t)N * 128));
    unsigned int* B2 = (unsigned int*)(ws + alloc(2 * (size_t)N * 128));
    unsigned int* B3 = (unsigned int*)(ws + alloc(2 * (size_t)N * 128));
    unsigned int* B4 = (unsigned int*)(ws + alloc(2 * (size_t)N * 128));
    unsigned int* B5 = (unsigned int*)(ws + alloc(2 * (size_t)N * 128));

    hipMemsetAsync(ws, 0, zero_bytes, stream);

    dim3 b256(256);
    k_combine<<<dim3((4 * 128 * 160 + 255) / 256), b256, 0, stream>>>(W0, AT0, 144, 160);
    k_combine<<<dim3((4 * 128 * 128 + 255) / 256), b256, 0, stream>>>(W1, AT1, 128, 128);
    k_headsT<<<dim3((128 * 128 + 255) / 256), b256, 0, stream>>>(Wmu, Wlv, ATH);

    // K1: layer-0 pair-GEMM tiles + tail atomics
    int G64 = (N + 63) / 64;
    int total = 2 * G64;
    int EPC = (E + total - 1) / total;
    k_mega<<<dim3(total), b256, 0, stream>>>(src, dst, ew, deg, cnt, rank, x, pe, AT0,
                                             (unsigned short*)B1, (unsigned short*)B2,
                                             (unsigned short*)B3, (unsigned short*)B4,
                                             N, E, EPC);

    int nb = (N + 1023) / 1024;
    k_dis_blocksum<<<dim3(nb), dim3(1024), 0, stream>>>(deg, cnt, bsum, N);
    k_scan_bsum<<<dim3(1), dim3(128), 0, stream>>>(bsum, nb);
    k_scan<<<dim3(nb), dim3(1024), 0, stream>>>(cnt, bsum, rowp, N);
    k_build_csr<<<dim3((E + 511) / 512), b256, 0, stream>>>(src, dst, ew, deg, rowp, rank, pack, E);

    dim3 gp((N + 7) / 8);
    const long long* packll = (const long long*)pack;
    uint4* B1v = (uint4*)B1; uint4* B2v = (uint4*)B2; uint4* B3v = (uint4*)B3;
    uint4* B4v = (uint4*)B4; uint4* B5v = (uint4*)B5;

    // layer 0 (Horner): B1=Z3 B2=Z2 B3=Z1 B4=Z0 (from K1)
    k_prop<0><<<gp, b256, 0, stream>>>(B1v, B2v, B5v, nullptr, rowp, packll, N, E);   // B5 = Z2 + P Z3
    k_prop<0><<<gp, b256, 0, stream>>>(B5v, B3v, B1v, nullptr, rowp, packll, N, E);   // B1 = Z1 + P B5
    k_prop<1><<<gp, b256, 0, stream>>>(B1v, B4v, B2v, b0, rowp, packll, N, E);        // B2 = h1

    // layer 1 (powers form): U1 = P h1, U2 = P U1, U3 = P U2
    k_prop<2><<<gp, b256, 0, stream>>>(B2v, nullptr, B3v, nullptr, rowp, packll, N, E);  // B3 = U1
    k_prop<2><<<gp, b256, 0, stream>>>(B3v, nullptr, B4v, nullptr, rowp, packll, N, E);  // B4 = U2
    k_prop<2><<<gp, b256, 0, stream>>>(B4v, nullptr, B5v, nullptr, rowp, packll, N, E);  // B5 = U3

    // fused: h2 = relu([h1|U1|U2|U3]@AT1 + b1) -> heads -> d_out
    k_gemm_l1_heads<<<dim3(G64), b256, 0, stream>>>((const unsigned short*)B2, (const unsigned short*)B3,
                                                    (const unsigned short*)B4, (const unsigned short*)B5,
                                                    AT1, ATH, b1, bmu, blv, (float*)d_out, N);
}

// Round 10
// 738.188 us; speedup vs baseline: 1.0427x; 1.0427x over previous
//
#include <hip/hip_runtime.h>
#include <hip/hip_bf16.h>

typedef float f32x4 __attribute__((ext_vector_type(4)));
typedef unsigned short u16x8 __attribute__((ext_vector_type(8)));

static __device__ __forceinline__ void mfma16(f32x4& c, const u16x8& a, const u16x8& b) {
    asm("v_mfma_f32_16x16x32_bf16 %0, %1, %2, %0" : "+v"(c) : "v"(a), "v"(b));
}

static __device__ __forceinline__ unsigned short f2bf(float f) {
    __hip_bfloat16 h = __float2bfloat16(f);
    return *reinterpret_cast<unsigned short*>(&h);
}

static __device__ __forceinline__ float bflo(unsigned int v) { return __uint_as_float(v << 16); }
static __device__ __forceinline__ float bfhi(unsigned int v) { return __uint_as_float(v & 0xffff0000u); }

// ---------------- small prep kernels ----------------

__global__ __launch_bounds__(1024) void k_dis_blocksum(float* deg, const int* __restrict__ cnt,
                                                       int* bsum, int N) {
    __shared__ int sd[1024];
    int i = blockIdx.x * 1024 + threadIdx.x;
    if (i < N) {
        float d = deg[i];
        deg[i] = (d > 0.f) ? rsqrtf(d) : 0.f;
    }
    sd[threadIdx.x] = (i < N) ? cnt[i] : 0;
    __syncthreads();
    for (int s = 512; s > 0; s >>= 1) {
        if (threadIdx.x < s) sd[threadIdx.x] += sd[threadIdx.x + s];
        __syncthreads();
    }
    if (threadIdx.x == 0) bsum[blockIdx.x] = sd[0];
}

__global__ __launch_bounds__(128) void k_scan_bsum(int* bsum, int nb) {
    __shared__ int sd[128];
    int t = threadIdx.x;
    int v = (t < nb) ? bsum[t] : 0;
    sd[t] = v;
    __syncthreads();
    for (int d = 1; d < 128; d <<= 1) {
        int x = (t >= d) ? sd[t - d] : 0;
        __syncthreads();
        sd[t] += x;
        __syncthreads();
    }
    if (t < nb) bsum[t] = sd[t] - v;  // exclusive block offsets
}

__global__ __launch_bounds__(1024) void k_scan(const int* __restrict__ cnt, const int* __restrict__ bsum,
                                               int* rowp, int N) {
    __shared__ int sd[1024];
    int i = blockIdx.x * 1024 + threadIdx.x;
    int v = (i < N) ? cnt[i] : 0;
    sd[threadIdx.x] = v;
    __syncthreads();
    for (int d = 1; d < 1024; d <<= 1) {
        int x = (threadIdx.x >= d) ? sd[threadIdx.x - d] : 0;
        __syncthreads();
        sd[threadIdx.x] += x;
        __syncthreads();
    }
    if (i < N) rowp[i] = sd[threadIdx.x] - v + bsum[blockIdx.x];
}

// atomic-free CSR fill: pos = rowp[dst] + rank (u8, captured during mega's counting atomics)
__global__ __launch_bounds__(256) void k_build_csr(const int* __restrict__ src, const int* __restrict__ dst,
                                                   const float* __restrict__ ew, const float* __restrict__ dis,
                                                   const int* __restrict__ rowp,
                                                   const unsigned char* __restrict__ rank,
                                                   int2* __restrict__ pack, int E) {
    int base = blockIdx.x * 512 + threadIdx.x;
#pragma unroll
    for (int u = 0; u < 2; u++) {
        int e = base + u * 256;
        if (e < E) {
            int s = src[e], d = dst[e];
            float w = (s == d) ? 0.f : ew[e];
            float wh = -dis[s] * w * dis[d];
            int pos = rowp[d] + (int)rank[e];
            int2 p;
            p.x = s;
            p.y = __float_as_int(wh);
            pack[pos] = p;
        }
    }
}

// ---------------- weight prep ----------------

// AT[sel][n][kk] = A_sel[kk][n] (transposed, bf16), A0=W0-W2, A1=W1-3W3, A2=2W2, A3=4W3
__global__ __launch_bounds__(256) void k_combine(const float* __restrict__ W, unsigned short* __restrict__ AT,
                                                 int D, int KPAD) {
    int i = blockIdx.x * 256 + threadIdx.x;
    int tot = 4 * 128 * KPAD;
    if (i >= tot) return;
    int sel = i / (128 * KPAD);
    int rem = i - sel * 128 * KPAD;
    int n = rem / KPAD;
    int kk = rem - n * KPAD;
    float v = 0.f;
    if (kk < D) {
        if (sel == 0)      v = W[(0 * D + kk) * 128 + n] - W[(2 * D + kk) * 128 + n];
        else if (sel == 1) v = W[(1 * D + kk) * 128 + n] - 3.f * W[(3 * D + kk) * 128 + n];
        else if (sel == 2) v = 2.f * W[(2 * D + kk) * 128 + n];
        else               v = 4.f * W[(3 * D + kk) * 128 + n];
    }
    AT[i] = f2bf(v);
}

__global__ __launch_bounds__(256) void k_headsT(const float* __restrict__ Wmu, const float* __restrict__ Wlv,
                                                unsigned short* __restrict__ AT) {
    int i = blockIdx.x * 256 + threadIdx.x;
    if (i >= 128 * 128) return;
    int n = i >> 7, kk = i & 127;
    float v = (n < 64) ? Wmu[kk * 64 + n] : Wlv[kk * 64 + (n - 64)];
    AT[i] = f2bf(v);
}

// ---------------- reg-B pair GEMM body (mega layer-0): BM=64, BN=128, 2 weights/block ----------------

template <int KPAD>
static __device__ __forceinline__ void gemm_pair_regB(const float* __restrict__ x,
                                                      const float* __restrict__ pe,
                                                      const unsigned short* __restrict__ Bta,
                                                      const unsigned short* __restrict__ Btb,
                                                      unsigned short* __restrict__ outA,
                                                      unsigned short* __restrict__ outB,
                                                      int N, int bx, unsigned short* As) {
    constexpr int LP = KPAD + 8;
    const int tid = threadIdx.x;
    const int row0 = bx * 64;

    {   // stage A tile (64 x KPAD) = concat(x, pe, pad) -> bf16
        constexpr int TOT = 64 * KPAD;
        for (int c = tid * 8; c < TOT; c += 256 * 8) {
            int r = c / KPAD;
            int k = c - r * KPAD;
            int gr = row0 + r;
            if (gr > N - 1) gr = N - 1;
            u16x8 v;
            if (k < 128) {
                float4 f0 = *reinterpret_cast<const float4*>(&x[(size_t)gr * 128 + k]);
                float4 f1 = *reinterpret_cast<const float4*>(&x[(size_t)gr * 128 + k + 4]);
                v[0] = f2bf(f0.x); v[1] = f2bf(f0.y); v[2] = f2bf(f0.z); v[3] = f2bf(f0.w);
                v[4] = f2bf(f1.x); v[5] = f2bf(f1.y); v[6] = f2bf(f1.z); v[7] = f2bf(f1.w);
            } else if (k < 144) {
                float4 f0 = *reinterpret_cast<const float4*>(&pe[(size_t)gr * 16 + (k - 128)]);
                float4 f1 = *reinterpret_cast<const float4*>(&pe[(size_t)gr * 16 + (k - 124)]);
                v[0] = f2bf(f0.x); v[1] = f2bf(f0.y); v[2] = f2bf(f0.z); v[3] = f2bf(f0.w);
                v[4] = f2bf(f1.x); v[5] = f2bf(f1.y); v[6] = f2bf(f1.z); v[7] = f2bf(f1.w);
            } else {
                v = (u16x8){0, 0, 0, 0, 0, 0, 0, 0};
            }
            *reinterpret_cast<u16x8*>(&As[r * LP + k]) = v;
        }
    }
    __syncthreads();

    const int wave = tid >> 6, lane = tid & 63;
    const int wm = wave & 1, ww = wave >> 1;
    const int lr = lane & 15, lg = lane >> 4;
    const unsigned short* Bw = ww ? Btb : Bta;

    f32x4 acc[2][8];
#pragma unroll
    for (int i = 0; i < 2; i++)
#pragma unroll
        for (int j = 0; j < 8; j++) acc[i][j] = (f32x4){0.f, 0.f, 0.f, 0.f};

    asm volatile("s_nop 7"
                 : "+v"(acc[0][0]), "+v"(acc[0][4]), "+v"(acc[1][0]), "+v"(acc[1][4]));

    constexpr int KS = KPAD / 32;
#pragma unroll
    for (int ks = 0; ks < KS; ks++) {
        u16x8 a0 = *reinterpret_cast<const u16x8*>(&As[(wm * 32 + lr) * LP + ks * 32 + lg * 8]);
        u16x8 a1 = *reinterpret_cast<const u16x8*>(&As[(wm * 32 + 16 + lr) * LP + ks * 32 + lg * 8]);
#pragma unroll
        for (int g = 0; g < 2; g++) {
            u16x8 b[4];
#pragma unroll
            for (int j = 0; j < 4; j++)
                b[j] = *reinterpret_cast<const u16x8*>(&Bw[(size_t)((g * 4 + j) * 16 + lr) * KPAD + ks * 32 + lg * 8]);
#pragma unroll
            for (int j = 0; j < 4; j++) {
                mfma16(acc[0][g * 4 + j], a0, b[j]);
                mfma16(acc[1][g * 4 + j], a1, b[j]);
            }
        }
    }

    asm volatile("s_nop 7\n\ts_nop 7\n\ts_nop 7"
                 : "+v"(acc[0][0]), "+v"(acc[0][4]), "+v"(acc[1][0]), "+v"(acc[1][4]));

    unsigned short* outp = ww ? outB : outA;
#pragma unroll
    for (int fm = 0; fm < 2; fm++)
#pragma unroll
        for (int fn = 0; fn < 8; fn++)
#pragma unroll
            for (int i = 0; i < 4; i++) {
                int r = row0 + wm * 32 + fm * 16 + lg * 4 + i;
                if (r < N) outp[(size_t)r * 128 + fn * 16 + lr] = f2bf(acc[fm][fn][i]);
            }
}

// ---------------- K1 mega: {layer-0 pair-GEMM tile, fused concat} then {deg FF + cnt/rank atomics} ----------------

__global__ __launch_bounds__(256, 4) void k_mega(const int* __restrict__ src, const int* __restrict__ dst,
                                                 const float* __restrict__ ew,
                                                 float* deg, int* cnt, unsigned char* __restrict__ rank,
                                                 const float* __restrict__ x, const float* __restrict__ pe,
                                                 const unsigned short* __restrict__ AT0,
                                                 unsigned short* __restrict__ oZ3, unsigned short* __restrict__ oZ2,
                                                 unsigned short* __restrict__ oZ1, unsigned short* __restrict__ oZ0,
                                                 int N, int E, int EPC) {
    __shared__ __align__(16) unsigned short As[64 * 168];
    const int bid = blockIdx.x;

    {
        int P = bid & 1;
        int bx = bid >> 1;
        const unsigned short* Bta = AT0 + (size_t)(3 - 2 * P) * 128 * 160;
        const unsigned short* Btb = AT0 + (size_t)(2 - 2 * P) * 128 * 160;
        unsigned short* outA = (P == 0) ? oZ3 : oZ1;
        unsigned short* outB = (P == 0) ? oZ2 : oZ0;
        gemm_pair_regB<160>(x, pe, Bta, Btb, outA, outB, N, bx, As);
    }

    {
        int e0 = bid * EPC;
        int e1 = e0 + EPC;
        if (e1 > E) e1 = E;
        for (int e = e0 + threadIdx.x; e < e1; e += 256) {
            int s = src[e], d = dst[e];
            float w = (s == d) ? 0.f : ew[e];
            atomicAdd(&deg[s], w);
            rank[e] = (unsigned char)atomicAdd(&cnt[d], 1);
        }
    }
}

// ---------------- fused layer-1 GEMM (K=512 powers form) + heads ----------------
// h2 = relu([h1|U1|U2|U3] @ [A0;A1;A2;A3] + b1)  (h2 kept in LDS), then [mu|lv] = h2 @ ATH^T + bias.

__global__ __launch_bounds__(256, 4) void k_gemm_l1_heads(const unsigned short* __restrict__ h1,
                                                          const unsigned short* __restrict__ U1,
                                                          const unsigned short* __restrict__ U2,
                                                          const unsigned short* __restrict__ U3,
                                                          const unsigned short* __restrict__ AT1,
                                                          const unsigned short* __restrict__ ATH,
                                                          const float* __restrict__ b1,
                                                          const float* __restrict__ bmu,
                                                          const float* __restrict__ blv,
                                                          float* __restrict__ out, int N) {
    constexpr int LP = 136;
    __shared__ __align__(16) unsigned short As[64 * LP];
    const int tid = threadIdx.x;
    const int row0 = blockIdx.x * 64;
    const int wave = tid >> 6, lane = tid & 63;
    const int wm = wave & 1, wn = wave >> 1;
    const int lr = lane & 15, lg = lane >> 4;

    f32x4 acc[2][4];
#pragma unroll
    for (int i = 0; i < 2; i++)
#pragma unroll
        for (int j = 0; j < 4; j++) acc[i][j] = (f32x4){0.f, 0.f, 0.f, 0.f};

#pragma unroll 4
    for (int seg = 0; seg < 4; seg++) {
        const unsigned short* sp = (seg == 0) ? h1 : (seg == 1) ? U1 : (seg == 2) ? U2 : U3;
        for (int c = tid * 8; c < 64 * 128; c += 256 * 8) {
            int r = c >> 7;
            int k = c & 127;
            int gr = row0 + r;
            if (gr > N - 1) gr = N - 1;
            u16x8 v = *reinterpret_cast<const u16x8*>(&sp[(size_t)gr * 128 + k]);
            *reinterpret_cast<u16x8*>(&As[r * LP + k]) = v;
        }
        __syncthreads();
        const unsigned short* Bseg = AT1 + (size_t)seg * 128 * 128;
#pragma unroll
        for (int ks = 0; ks < 4; ks++) {
            u16x8 a0 = *reinterpret_cast<const u16x8*>(&As[(wm * 32 + lr) * LP + ks * 32 + lg * 8]);
            u16x8 a1 = *reinterpret_cast<const u16x8*>(&As[(wm * 32 + 16 + lr) * LP + ks * 32 + lg * 8]);
            u16x8 b[4];
#pragma unroll
            for (int j = 0; j < 4; j++)
                b[j] = *reinterpret_cast<const u16x8*>(&Bseg[(size_t)((wn * 64 + j * 16 + lr)) * 128 + ks * 32 + lg * 8]);
#pragma unroll
            for (int j = 0; j < 4; j++) {
                mfma16(acc[0][j], a0, b[j]);
                mfma16(acc[1][j], a1, b[j]);
            }
        }
        __syncthreads();  // protect As before next stage overwrites
    }

    asm volatile("s_nop 7\n\ts_nop 7\n\ts_nop 7"
                 : "+v"(acc[0][0]), "+v"(acc[0][1]), "+v"(acc[0][2]), "+v"(acc[0][3]),
                   "+v"(acc[1][0]), "+v"(acc[1][1]), "+v"(acc[1][2]), "+v"(acc[1][3]));

#pragma unroll
    for (int fm = 0; fm < 2; fm++)
#pragma unroll
        for (int fn = 0; fn < 4; fn++)
#pragma unroll
            for (int i = 0; i < 4; i++) {
                int rl = wm * 32 + fm * 16 + lg * 4 + i;
                int c = wn * 64 + fn * 16 + lr;
                float v = fmaxf(acc[fm][fn][i] + b1[c], 0.f);
                As[rl * LP + c] = f2bf(v);
            }
    __syncthreads();

    // heads: [mu|lv] = h2(LDS) @ ATH^T, K=128
    f32x4 acc2[2][4];
#pragma unroll
    for (int i = 0; i < 2; i++)
#pragma unroll
        for (int j = 0; j < 4; j++) acc2[i][j] = (f32x4){0.f, 0.f, 0.f, 0.f};

    asm volatile("s_nop 7"
                 : "+v"(acc2[0][0]), "+v"(acc2[0][1]), "+v"(acc2[1][0]), "+v"(acc2[1][1]));

#pragma unroll
    for (int ks = 0; ks < 4; ks++) {
        u16x8 a0 = *reinterpret_cast<const u16x8*>(&As[(wm * 32 + lr) * LP + ks * 32 + lg * 8]);
        u16x8 a1 = *reinterpret_cast<const u16x8*>(&As[(wm * 32 + 16 + lr) * LP + ks * 32 + lg * 8]);
        u16x8 b[4];
#pragma unroll
        for (int j = 0; j < 4; j++)
            b[j] = *reinterpret_cast<const u16x8*>(&ATH[(size_t)(wn * 64 + j * 16 + lr) * 128 + ks * 32 + lg * 8]);
#pragma unroll
        for (int j = 0; j < 4; j++) {
            mfma16(acc2[0][j], a0, b[j]);
            mfma16(acc2[1][j], a1, b[j]);
        }
    }

    asm volatile("s_nop 7\n\ts_nop 7\n\ts_nop 7"
                 : "+v"(acc2[0][0]), "+v"(acc2[0][1]), "+v"(acc2[1][0]), "+v"(acc2[1][1]));

#pragma unroll
    for (int fm = 0; fm < 2; fm++)
#pragma unroll
        for (int fn = 0; fn < 4; fn++)
#pragma unroll
            for (int i = 0; i < 4; i++) {
                int r = row0 + wm * 32 + fm * 16 + lg * 4 + i;
                if (r < N) {
                    int c = wn * 64 + fn * 16 + lr;
                    if (c < 64) out[(size_t)r * 64 + c] = acc2[fm][fn][i] + bmu[c];
                    else out[(size_t)N * 64 + (size_t)r * 64 + (c - 64)] = acc2[fm][fn][i] + blv[c - 64];
                }
            }
}

// ---------------- sparse prop v3 (round-8 structure): quarter-wave split, straight-line unroll ----------------
// 4 groups of 16 lanes; group g handles CSR slots e = beg+g, +4, ... ; lane loads uint4 (16B)
// so 16 lanes cover one full 256B row. Cross-group reduce: shfl_xor 16, 32.

template <int MODE>  // 0: z + P t ; 1: relu(z + P t + bias) ; 2: pure P t
__global__ __launch_bounds__(256) void k_prop(const uint4* __restrict__ tin4,
                                              const uint4* __restrict__ z4,
                                              uint4* __restrict__ tout4,
                                              const float* __restrict__ bias,
                                              const int* __restrict__ rowp,
                                              const long long* __restrict__ pack,
                                              int N, int E) {
    int wave = threadIdx.x >> 6, lane = threadIdx.x & 63;
    int node = blockIdx.x * 4 + wave;
    if (node >= N) return;
    int beg = rowp[node];
    int end = (node == N - 1) ? E : rowp[node + 1];
    const int grp = lane >> 4, li = lane & 15;
    float s0 = 0.f, s1 = 0.f, s2 = 0.f, s3 = 0.f, s4 = 0.f, s5 = 0.f, s6 = 0.f, s7 = 0.f;
    int e = beg + grp;
    for (; e + 4 < end; e += 8) {
        long long qa = __builtin_nontemporal_load(pack + e);
        long long qb = __builtin_nontemporal_load(pack + e + 4);
        uint4 va = tin4[(size_t)(unsigned int)qa * 16 + li];
        uint4 vb = tin4[(size_t)(unsigned int)qb * 16 + li];
        float wa = __uint_as_float((unsigned int)((unsigned long long)qa >> 32));
        float wb = __uint_as_float((unsigned int)((unsigned long long)qb >> 32));
        s0 = fmaf(wa, bflo(va.x), s0); s1 = fmaf(wa, bfhi(va.x), s1);
        s2 = fmaf(wa, bflo(va.y), s2); s3 = fmaf(wa, bfhi(va.y), s3);
        s4 = fmaf(wa, bflo(va.z), s4); s5 = fmaf(wa, bfhi(va.z), s5);
        s6 = fmaf(wa, bflo(va.w), s6); s7 = fmaf(wa, bfhi(va.w), s7);
        s0 = fmaf(wb, bflo(vb.x), s0); s1 = fmaf(wb, bfhi(vb.x), s1);
        s2 = fmaf(wb, bflo(vb.y), s2); s3 = fmaf(wb, bfhi(vb.y), s3);
        s4 = fmaf(wb, bflo(vb.z), s4); s5 = fmaf(wb, bfhi(vb.z), s5);
        s6 = fmaf(wb, bflo(vb.w), s6); s7 = fmaf(wb, bfhi(vb.w), s7);
    }
    for (; e < end; e += 4) {
        long long qa = __builtin_nontemporal_load(pack + e);
        uint4 va = tin4[(size_t)(unsigned int)qa * 16 + li];
        float wa = __uint_as_float((unsigned int)((unsigned long long)qa >> 32));
        s0 = fmaf(wa, bflo(va.x), s0); s1 = fmaf(wa, bfhi(va.x), s1);
        s2 = fmaf(wa, bflo(va.y), s2); s3 = fmaf(wa, bfhi(va.y), s3);
        s4 = fmaf(wa, bflo(va.z), s4); s5 = fmaf(wa, bfhi(va.z), s5);
        s6 = fmaf(wa, bflo(va.w), s6); s7 = fmaf(wa, bfhi(va.w), s7);
    }
    // reduce across the 4 groups (lanes with equal li)
    s0 += __shfl_xor(s0, 16); s1 += __shfl_xor(s1, 16);
    s2 += __shfl_xor(s2, 16); s3 += __shfl_xor(s3, 16);
    s4 += __shfl_xor(s4, 16); s5 += __shfl_xor(s5, 16);
    s6 += __shfl_xor(s6, 16); s7 += __shfl_xor(s7, 16);
    s0 += __shfl_xor(s0, 32); s1 += __shfl_xor(s1, 32);
    s2 += __shfl_xor(s2, 32); s3 += __shfl_xor(s3, 32);
    s4 += __shfl_xor(s4, 32); s5 += __shfl_xor(s5, 32);
    s6 += __shfl_xor(s6, 32); s7 += __shfl_xor(s7, 32);
    if (lane < 16) {
        float r0 = s0, r1 = s1, r2 = s2, r3 = s3, r4 = s4, r5 = s5, r6 = s6, r7 = s7;
        if (MODE != 2) {
            uint4 zv = z4[(size_t)node * 16 + li];
            r0 += bflo(zv.x); r1 += bfhi(zv.x); r2 += bflo(zv.y); r3 += bfhi(zv.y);
            r4 += bflo(zv.z); r5 += bfhi(zv.z); r6 += bflo(zv.w); r7 += bfhi(zv.w);
        }
        if (MODE == 1) {
            const float* bp = bias + li * 8;
            r0 = fmaxf(r0 + bp[0], 0.f); r1 = fmaxf(r1 + bp[1], 0.f);
            r2 = fmaxf(r2 + bp[2], 0.f); r3 = fmaxf(r3 + bp[3], 0.f);
            r4 = fmaxf(r4 + bp[4], 0.f); r5 = fmaxf(r5 + bp[5], 0.f);
            r6 = fmaxf(r6 + bp[6], 0.f); r7 = fmaxf(r7 + bp[7], 0.f);
        }
        uint4 o;
        o.x = (unsigned int)f2bf(r0) | ((unsigned int)f2bf(r1) << 16);
        o.y = (unsigned int)f2bf(r2) | ((unsigned int)f2bf(r3) << 16);
        o.z = (unsigned int)f2bf(r4) | ((unsigned int)f2bf(r5) << 16);
        o.w = (unsigned int)f2bf(r6) | ((unsigned int)f2bf(r7) << 16);
        tout4[(size_t)node * 16 + li] = o;
    }
}

// ---------------- launch ----------------

extern "C" void kernel_launch(void* const* d_in, const int* in_sizes, int n_in,
                              void* d_out, int out_size, void* d_ws, size_t ws_size,
                              hipStream_t stream) {
    const float* x   = (const float*)d_in[0];
    const int*   ei  = (const int*)d_in[1];
    const float* pe  = (const float*)d_in[2];
    const float* ew  = (const float*)d_in[3];
    const float* W0  = (const float*)d_in[4];
    const float* b0  = (const float*)d_in[5];
    const float* W1  = (const float*)d_in[6];
    const float* b1  = (const float*)d_in[7];
    const float* Wmu = (const float*)d_in[8];
    const float* bmu = (const float*)d_in[9];
    const float* Wlv = (const float*)d_in[10];
    const float* blv = (const float*)d_in[11];

    const int N = in_sizes[0] / 128;
    const int E = in_sizes[3];
    const int* src = ei;
    const int* dst = ei + E;

    char* ws = (char*)d_ws;
    size_t off = 0;
    auto alloc = [&](size_t bytes) {
        size_t o = off;
        off += (bytes + 1023) & ~(size_t)1023;
        return o;
    };
    float* deg = (float*)(ws + alloc(4 * (size_t)N));   // becomes dis in-place
    int* cnt   = (int*)(ws + alloc(4 * (size_t)N));
    size_t zero_bytes = off;                            // memset deg+cnt
    unsigned char* rank = (unsigned char*)(ws + alloc((size_t)E));
    int* rowp  = (int*)(ws + alloc(4 * (size_t)N));
    int* bsum  = (int*)(ws + alloc(4 * 128));
    unsigned short* AT0 = (unsigned short*)(ws + alloc(2 * 4 * 128 * 160));
    unsigned short* AT1 = (unsigned short*)(ws + alloc(2 * 4 * 128 * 128));
    unsigned short* ATH = (unsigned short*)(ws + alloc(2 * 128 * 128));
    int2* pack = (int2*)(ws + alloc(8 * (size_t)E));
    unsigned int* B1 = (unsigned int*)(ws + alloc(2 * (size_t)N * 128));
    unsigned int* B2 = (unsigned int*)(ws + alloc(2 * (size_t)N * 128));
    unsigned int* B3 = (unsigned int*)(ws + alloc(2 * (size_t)N * 128));
    unsigned int* B4 = (unsigned int*)(ws + alloc(2 * (size_t)N * 128));
    unsigned int* B5 = (unsigned int*)(ws + alloc(2 * (size_t)N * 128));

    hipMemsetAsync(ws, 0, zero_bytes, stream);

    dim3 b256(256);
    k_combine<<<dim3((4 * 128 * 160 + 255) / 256), b256, 0, stream>>>(W0, AT0, 144, 160);
    k_combine<<<dim3((4 * 128 * 128 + 255) / 256), b256, 0, stream>>>(W1, AT1, 128, 128);
    k_headsT<<<dim3((128 * 128 + 255) / 256), b256, 0, stream>>>(Wmu, Wlv, ATH);

    // K1: layer-0 pair-GEMM tiles + tail atomics
    int G64 = (N + 63) / 64;
    int total = 2 * G64;
    int EPC = (E + total - 1) / total;
    k_mega<<<dim3(total), b256, 0, stream>>>(src, dst, ew, deg, cnt, rank, x, pe, AT0,
                                             (unsigned short*)B1, (unsigned short*)B2,
                                             (unsigned short*)B3, (unsigned short*)B4,
                                             N, E, EPC);

    int nb = (N + 1023) / 1024;
    k_dis_blocksum<<<dim3(nb), dim3(1024), 0, stream>>>(deg, cnt, bsum, N);
    k_scan_bsum<<<dim3(1), dim3(128), 0, stream>>>(bsum, nb);
    k_scan<<<dim3(nb), dim3(1024), 0, stream>>>(cnt, bsum, rowp, N);
    k_build_csr<<<dim3((E + 511) / 512), b256, 0, stream>>>(src, dst, ew, deg, rowp, rank, pack, E);

    dim3 gp((N + 3) / 4);
    const long long* packll = (const long long*)pack;
    uint4* B1v = (uint4*)B1; uint4* B2v = (uint4*)B2; uint4* B3v = (uint4*)B3;
    uint4* B4v = (uint4*)B4; uint4* B5v = (uint4*)B5;

    // layer 0 (Horner): B1=Z3 B2=Z2 B3=Z1 B4=Z0 (from K1)
    k_prop<0><<<gp, b256, 0, stream>>>(B1v, B2v, B5v, nullptr, rowp, packll, N, E);   // B5 = Z2 + P Z3
    k_prop<0><<<gp, b256, 0, stream>>>(B5v, B3v, B1v, nullptr, rowp, packll, N, E);   // B1 = Z1 + P B5
    k_prop<1><<<gp, b256, 0, stream>>>(B1v, B4v, B2v, b0, rowp, packll, N, E);        // B2 = h1

    // layer 1 (powers form): U1 = P h1, U2 = P U1, U3 = P U2
    k_prop<2><<<gp, b256, 0, stream>>>(B2v, nullptr, B3v, nullptr, rowp, packll, N, E);  // B3 = U1
    k_prop<2><<<gp, b256, 0, stream>>>(B3v, nullptr, B4v, nullptr, rowp, packll, N, E);  // B4 = U2
    k_prop<2><<<gp, b256, 0, stream>>>(B4v, nullptr, B5v, nullptr, rowp, packll, N, E);  // B5 = U3

    // fused: h2 = relu([h1|U1|U2|U3]@AT1 + b1) -> heads -> d_out
    k_gemm_l1_heads<<<dim3(G64), b256, 0, stream>>>((const unsigned short*)B2, (const unsigned short*)B3,
                                                    (const unsigned short*)B4, (const unsigned short*)B5,
                                                    AT1, ATH, b1, bmu, blv, (float*)d_out, N);
}

// Round 11
// 695.356 us; speedup vs baseline: 1.1069x; 1.0616x over previous
//
#include <hip/hip_runtime.h>
#include <hip/hip_bf16.h>

typedef float f32x4 __attribute__((ext_vector_type(4)));
typedef unsigned short u16x8 __attribute__((ext_vector_type(8)));

static __device__ __forceinline__ void mfma16(f32x4& c, const u16x8& a, const u16x8& b) {
    asm("v_mfma_f32_16x16x32_bf16 %0, %1, %2, %0" : "+v"(c) : "v"(a), "v"(b));
}

static __device__ __forceinline__ unsigned short f2bf(float f) {
    __hip_bfloat16 h = __float2bfloat16(f);
    return *reinterpret_cast<unsigned short*>(&h);
}

static __device__ __forceinline__ float bflo(unsigned int v) { return __uint_as_float(v << 16); }
static __device__ __forceinline__ float bfhi(unsigned int v) { return __uint_as_float(v & 0xffff0000u); }

// ---------------- small prep kernels ----------------

__global__ __launch_bounds__(1024) void k_dis_blocksum(float* deg, const int* __restrict__ cnt,
                                                       int* bsum, int N) {
    __shared__ int sd[1024];
    int i = blockIdx.x * 1024 + threadIdx.x;
    if (i < N) {
        float d = deg[i];
        deg[i] = (d > 0.f) ? rsqrtf(d) : 0.f;
    }
    sd[threadIdx.x] = (i < N) ? cnt[i] : 0;
    __syncthreads();
    for (int s = 512; s > 0; s >>= 1) {
        if (threadIdx.x < s) sd[threadIdx.x] += sd[threadIdx.x + s];
        __syncthreads();
    }
    if (threadIdx.x == 0) bsum[blockIdx.x] = sd[0];
}

__global__ __launch_bounds__(128) void k_scan_bsum(int* bsum, int nb) {
    __shared__ int sd[128];
    int t = threadIdx.x;
    int v = (t < nb) ? bsum[t] : 0;
    sd[t] = v;
    __syncthreads();
    for (int d = 1; d < 128; d <<= 1) {
        int x = (t >= d) ? sd[t - d] : 0;
        __syncthreads();
        sd[t] += x;
        __syncthreads();
    }
    if (t < nb) bsum[t] = sd[t] - v;  // exclusive block offsets
}

__global__ __launch_bounds__(1024) void k_scan(const int* __restrict__ cnt, const int* __restrict__ bsum,
                                               int* rowp, int N) {
    __shared__ int sd[1024];
    int i = blockIdx.x * 1024 + threadIdx.x;
    int v = (i < N) ? cnt[i] : 0;
    sd[threadIdx.x] = v;
    __syncthreads();
    for (int d = 1; d < 1024; d <<= 1) {
        int x = (threadIdx.x >= d) ? sd[threadIdx.x - d] : 0;
        __syncthreads();
        sd[threadIdx.x] += x;
        __syncthreads();
    }
    if (i < N) rowp[i] = sd[threadIdx.x] - v + bsum[blockIdx.x];
}

// atomic-free CSR fill: pos = rowp[dst] + rank (u8), unroll 4 for scatter MLP
__global__ __launch_bounds__(256) void k_build_csr(const int* __restrict__ src, const int* __restrict__ dst,
                                                   const float* __restrict__ ew, const float* __restrict__ dis,
                                                   const int* __restrict__ rowp,
                                                   const unsigned char* __restrict__ rank,
                                                   int2* __restrict__ pack, int E) {
    int base = blockIdx.x * 1024 + threadIdx.x;
#pragma unroll
    for (int u = 0; u < 4; u++) {
        int e = base + u * 256;
        if (e < E) {
            int s = src[e], d = dst[e];
            float w = (s == d) ? 0.f : ew[e];
            float wh = -dis[s] * w * dis[d];
            int pos = rowp[d] + (int)rank[e];
            int2 p;
            p.x = s;
            p.y = __float_as_int(wh);
            pack[pos] = p;
        }
    }
}

// ---------------- weight prep (fused: AT0 | AT1 | ATH) ----------------
// AT[sel][n][kk] = A_sel[kk][n] (transposed, bf16), A0=W0-W2, A1=W1-3W3, A2=2W2, A3=4W3

static __device__ __forceinline__ void combine_elem(const float* __restrict__ W,
                                                    unsigned short* __restrict__ AT,
                                                    int i, int D, int KPAD) {
    int sel = i / (128 * KPAD);
    int rem = i - sel * 128 * KPAD;
    int n = rem / KPAD;
    int kk = rem - n * KPAD;
    float v = 0.f;
    if (kk < D) {
        if (sel == 0)      v = W[(0 * D + kk) * 128 + n] - W[(2 * D + kk) * 128 + n];
        else if (sel == 1) v = W[(1 * D + kk) * 128 + n] - 3.f * W[(3 * D + kk) * 128 + n];
        else if (sel == 2) v = 2.f * W[(2 * D + kk) * 128 + n];
        else               v = 4.f * W[(3 * D + kk) * 128 + n];
    }
    AT[i] = f2bf(v);
}

__global__ __launch_bounds__(256) void k_prep_weights(const float* __restrict__ W0,
                                                      const float* __restrict__ W1,
                                                      const float* __restrict__ Wmu,
                                                      const float* __restrict__ Wlv,
                                                      unsigned short* __restrict__ AT0,
                                                      unsigned short* __restrict__ AT1,
                                                      unsigned short* __restrict__ ATH) {
    constexpr int T0 = 4 * 128 * 160;
    constexpr int T1 = 4 * 128 * 128;
    int i = blockIdx.x * 256 + threadIdx.x;
    if (i < T0) {
        combine_elem(W0, AT0, i, 144, 160);
    } else if (i < T0 + T1) {
        combine_elem(W1, AT1, i - T0, 128, 128);
    } else if (i < T0 + T1 + 128 * 128) {
        int j = i - T0 - T1;
        int n = j >> 7, kk = j & 127;
        float v = (n < 64) ? Wmu[kk * 64 + n] : Wlv[kk * 64 + (n - 64)];
        ATH[j] = f2bf(v);
    }
}

// ---------------- reg-B pair GEMM body (mega layer-0): BM=64, BN=128, 2 weights/block ----------------

template <int KPAD>
static __device__ __forceinline__ void gemm_pair_regB(const float* __restrict__ x,
                                                      const float* __restrict__ pe,
                                                      const unsigned short* __restrict__ Bta,
                                                      const unsigned short* __restrict__ Btb,
                                                      unsigned short* __restrict__ outA,
                                                      unsigned short* __restrict__ outB,
                                                      int N, int bx, unsigned short* As) {
    constexpr int LP = KPAD + 8;
    const int tid = threadIdx.x;
    const int row0 = bx * 64;

    {   // stage A tile (64 x KPAD) = concat(x, pe, pad) -> bf16
        constexpr int TOT = 64 * KPAD;
        for (int c = tid * 8; c < TOT; c += 256 * 8) {
            int r = c / KPAD;
            int k = c - r * KPAD;
            int gr = row0 + r;
            if (gr > N - 1) gr = N - 1;
            u16x8 v;
            if (k < 128) {
                float4 f0 = *reinterpret_cast<const float4*>(&x[(size_t)gr * 128 + k]);
                float4 f1 = *reinterpret_cast<const float4*>(&x[(size_t)gr * 128 + k + 4]);
                v[0] = f2bf(f0.x); v[1] = f2bf(f0.y); v[2] = f2bf(f0.z); v[3] = f2bf(f0.w);
                v[4] = f2bf(f1.x); v[5] = f2bf(f1.y); v[6] = f2bf(f1.z); v[7] = f2bf(f1.w);
            } else if (k < 144) {
                float4 f0 = *reinterpret_cast<const float4*>(&pe[(size_t)gr * 16 + (k - 128)]);
                float4 f1 = *reinterpret_cast<const float4*>(&pe[(size_t)gr * 16 + (k - 124)]);
                v[0] = f2bf(f0.x); v[1] = f2bf(f0.y); v[2] = f2bf(f0.z); v[3] = f2bf(f0.w);
                v[4] = f2bf(f1.x); v[5] = f2bf(f1.y); v[6] = f2bf(f1.z); v[7] = f2bf(f1.w);
            } else {
                v = (u16x8){0, 0, 0, 0, 0, 0, 0, 0};
            }
            *reinterpret_cast<u16x8*>(&As[r * LP + k]) = v;
        }
    }
    __syncthreads();

    const int wave = tid >> 6, lane = tid & 63;
    const int wm = wave & 1, ww = wave >> 1;
    const int lr = lane & 15, lg = lane >> 4;
    const unsigned short* Bw = ww ? Btb : Bta;

    f32x4 acc[2][8];
#pragma unroll
    for (int i = 0; i < 2; i++)
#pragma unroll
        for (int j = 0; j < 8; j++) acc[i][j] = (f32x4){0.f, 0.f, 0.f, 0.f};

    asm volatile("s_nop 7"
                 : "+v"(acc[0][0]), "+v"(acc[0][4]), "+v"(acc[1][0]), "+v"(acc[1][4]));

    constexpr int KS = KPAD / 32;
#pragma unroll
    for (int ks = 0; ks < KS; ks++) {
        u16x8 a0 = *reinterpret_cast<const u16x8*>(&As[(wm * 32 + lr) * LP + ks * 32 + lg * 8]);
        u16x8 a1 = *reinterpret_cast<const u16x8*>(&As[(wm * 32 + 16 + lr) * LP + ks * 32 + lg * 8]);
#pragma unroll
        for (int g = 0; g < 2; g++) {
            u16x8 b[4];
#pragma unroll
            for (int j = 0; j < 4; j++)
                b[j] = *reinterpret_cast<const u16x8*>(&Bw[(size_t)((g * 4 + j) * 16 + lr) * KPAD + ks * 32 + lg * 8]);
#pragma unroll
            for (int j = 0; j < 4; j++) {
                mfma16(acc[0][g * 4 + j], a0, b[j]);
                mfma16(acc[1][g * 4 + j], a1, b[j]);
            }
        }
    }

    asm volatile("s_nop 7\n\ts_nop 7\n\ts_nop 7"
                 : "+v"(acc[0][0]), "+v"(acc[0][4]), "+v"(acc[1][0]), "+v"(acc[1][4]));

    unsigned short* outp = ww ? outB : outA;
#pragma unroll
    for (int fm = 0; fm < 2; fm++)
#pragma unroll
        for (int fn = 0; fn < 8; fn++)
#pragma unroll
            for (int i = 0; i < 4; i++) {
                int r = row0 + wm * 32 + fm * 16 + lg * 4 + i;
                if (r < N) outp[(size_t)r * 128 + fn * 16 + lr] = f2bf(acc[fm][fn][i]);
            }
}

// ---------------- K1 mega: {layer-0 pair-GEMM tile, fused concat} then {deg FF + cnt/rank atomics} ----------------

__global__ __launch_bounds__(256, 4) void k_mega(const int* __restrict__ src, const int* __restrict__ dst,
                                                 const float* __restrict__ ew,
                                                 float* deg, int* cnt, unsigned char* __restrict__ rank,
                                                 const float* __restrict__ x, const float* __restrict__ pe,
                                                 const unsigned short* __restrict__ AT0,
                                                 unsigned short* __restrict__ oZ3, unsigned short* __restrict__ oZ2,
                                                 unsigned short* __restrict__ oZ1, unsigned short* __restrict__ oZ0,
                                                 int N, int E, int EPC) {
    __shared__ __align__(16) unsigned short As[64 * 168];
    const int bid = blockIdx.x;

    {
        int P = bid & 1;
        int bx = bid >> 1;
        const unsigned short* Bta = AT0 + (size_t)(3 - 2 * P) * 128 * 160;
        const unsigned short* Btb = AT0 + (size_t)(2 - 2 * P) * 128 * 160;
        unsigned short* outA = (P == 0) ? oZ3 : oZ1;
        unsigned short* outB = (P == 0) ? oZ2 : oZ0;
        gemm_pair_regB<160>(x, pe, Bta, Btb, outA, outB, N, bx, As);
    }

    {
        int e0 = bid * EPC;
        int e1 = e0 + EPC;
        if (e1 > E) e1 = E;
        for (int e = e0 + threadIdx.x; e < e1; e += 256) {
            int s = src[e], d = dst[e];
            float w = (s == d) ? 0.f : ew[e];
            atomicAdd(&deg[s], w);
            rank[e] = (unsigned char)atomicAdd(&cnt[d], 1);
        }
    }
}

// ---------------- fused layer-1 GEMM (K=512 powers form) + heads ----------------
// h2 = relu([h1|U1|U2|U3] @ [A0;A1;A2;A3] + b1)  (h2 kept in LDS), then [mu|lv] = h2 @ ATH^T + bias.

__global__ __launch_bounds__(256, 4) void k_gemm_l1_heads(const unsigned short* __restrict__ h1,
                                                          const unsigned short* __restrict__ U1,
                                                          const unsigned short* __restrict__ U2,
                                                          const unsigned short* __restrict__ U3,
                                                          const unsigned short* __restrict__ AT1,
                                                          const unsigned short* __restrict__ ATH,
                                                          const float* __restrict__ b1,
                                                          const float* __restrict__ bmu,
                                                          const float* __restrict__ blv,
                                                          float* __restrict__ out, int N) {
    constexpr int LP = 136;
    __shared__ __align__(16) unsigned short As[64 * LP];
    const int tid = threadIdx.x;
    const int row0 = blockIdx.x * 64;
    const int wave = tid >> 6, lane = tid & 63;
    const int wm = wave & 1, wn = wave >> 1;
    const int lr = lane & 15, lg = lane >> 4;

    f32x4 acc[2][4];
#pragma unroll
    for (int i = 0; i < 2; i++)
#pragma unroll
        for (int j = 0; j < 4; j++) acc[i][j] = (f32x4){0.f, 0.f, 0.f, 0.f};

#pragma unroll 4
    for (int seg = 0; seg < 4; seg++) {
        const unsigned short* sp = (seg == 0) ? h1 : (seg == 1) ? U1 : (seg == 2) ? U2 : U3;
        for (int c = tid * 8; c < 64 * 128; c += 256 * 8) {
            int r = c >> 7;
            int k = c & 127;
            int gr = row0 + r;
            if (gr > N - 1) gr = N - 1;
            u16x8 v = *reinterpret_cast<const u16x8*>(&sp[(size_t)gr * 128 + k]);
            *reinterpret_cast<u16x8*>(&As[r * LP + k]) = v;
        }
        __syncthreads();
        const unsigned short* Bseg = AT1 + (size_t)seg * 128 * 128;
#pragma unroll
        for (int ks = 0; ks < 4; ks++) {
            u16x8 a0 = *reinterpret_cast<const u16x8*>(&As[(wm * 32 + lr) * LP + ks * 32 + lg * 8]);
            u16x8 a1 = *reinterpret_cast<const u16x8*>(&As[(wm * 32 + 16 + lr) * LP + ks * 32 + lg * 8]);
            u16x8 b[4];
#pragma unroll
            for (int j = 0; j < 4; j++)
                b[j] = *reinterpret_cast<const u16x8*>(&Bseg[(size_t)((wn * 64 + j * 16 + lr)) * 128 + ks * 32 + lg * 8]);
#pragma unroll
            for (int j = 0; j < 4; j++) {
                mfma16(acc[0][j], a0, b[j]);
                mfma16(acc[1][j], a1, b[j]);
            }
        }
        __syncthreads();  // protect As before next stage overwrites
    }

    asm volatile("s_nop 7\n\ts_nop 7\n\ts_nop 7"
                 : "+v"(acc[0][0]), "+v"(acc[0][1]), "+v"(acc[0][2]), "+v"(acc[0][3]),
                   "+v"(acc[1][0]), "+v"(acc[1][1]), "+v"(acc[1][2]), "+v"(acc[1][3]));

#pragma unroll
    for (int fm = 0; fm < 2; fm++)
#pragma unroll
        for (int fn = 0; fn < 4; fn++)
#pragma unroll
            for (int i = 0; i < 4; i++) {
                int rl = wm * 32 + fm * 16 + lg * 4 + i;
                int c = wn * 64 + fn * 16 + lr;
                float v = fmaxf(acc[fm][fn][i] + b1[c], 0.f);
                As[rl * LP + c] = f2bf(v);
            }
    __syncthreads();

    // heads: [mu|lv] = h2(LDS) @ ATH^T, K=128
    f32x4 acc2[2][4];
#pragma unroll
    for (int i = 0; i < 2; i++)
#pragma unroll
        for (int j = 0; j < 4; j++) acc2[i][j] = (f32x4){0.f, 0.f, 0.f, 0.f};

    asm volatile("s_nop 7"
                 : "+v"(acc2[0][0]), "+v"(acc2[0][1]), "+v"(acc2[1][0]), "+v"(acc2[1][1]));

#pragma unroll
    for (int ks = 0; ks < 4; ks++) {
        u16x8 a0 = *reinterpret_cast<const u16x8*>(&As[(wm * 32 + lr) * LP + ks * 32 + lg * 8]);
        u16x8 a1 = *reinterpret_cast<const u16x8*>(&As[(wm * 32 + 16 + lr) * LP + ks * 32 + lg * 8]);
        u16x8 b[4];
#pragma unroll
        for (int j = 0; j < 4; j++)
            b[j] = *reinterpret_cast<const u16x8*>(&ATH[(size_t)(wn * 64 + j * 16 + lr) * 128 + ks * 32 + lg * 8]);
#pragma unroll
        for (int j = 0; j < 4; j++) {
            mfma16(acc2[0][j], a0, b[j]);
            mfma16(acc2[1][j], a1, b[j]);
        }
    }

    asm volatile("s_nop 7\n\ts_nop 7\n\ts_nop 7"
                 : "+v"(acc2[0][0]), "+v"(acc2[0][1]), "+v"(acc2[1][0]), "+v"(acc2[1][1]));

#pragma unroll
    for (int fm = 0; fm < 2; fm++)
#pragma unroll
        for (int fn = 0; fn < 4; fn++)
#pragma unroll
            for (int i = 0; i < 4; i++) {
                int r = row0 + wm * 32 + fm * 16 + lg * 4 + i;
                if (r < N) {
                    int c = wn * 64 + fn * 16 + lr;
                    if (c < 64) out[(size_t)r * 64 + c] = acc2[fm][fn][i] + bmu[c];
                    else out[(size_t)N * 64 + (size_t)r * 64 + (c - 64)] = acc2[fm][fn][i] + blv[c - 64];
                }
            }
}

// ---------------- sparse prop v3: quarter-wave split, straight-line unroll; pack kept cacheable ----------------

template <int MODE>  // 0: z + P t ; 1: relu(z + P t + bias) ; 2: pure P t
__global__ __launch_bounds__(256) void k_prop(const uint4* __restrict__ tin4,
                                              const uint4* __restrict__ z4,
                                              uint4* __restrict__ tout4,
                                              const float* __restrict__ bias,
                                              const int* __restrict__ rowp,
                                              const long long* __restrict__ pack,
                                              int N, int E) {
    int wave = threadIdx.x >> 6, lane = threadIdx.x & 63;
    int node = blockIdx.x * 4 + wave;
    if (node >= N) return;
    int beg = rowp[node];
    int end = (node == N - 1) ? E : rowp[node + 1];
    const int grp = lane >> 4, li = lane & 15;
    float s0 = 0.f, s1 = 0.f, s2 = 0.f, s3 = 0.f, s4 = 0.f, s5 = 0.f, s6 = 0.f, s7 = 0.f;
    int e = beg + grp;
    for (; e + 4 < end; e += 8) {
        long long qa = pack[e];
        long long qb = pack[e + 4];
        uint4 va = tin4[(size_t)(unsigned int)qa * 16 + li];
        uint4 vb = tin4[(size_t)(unsigned int)qb * 16 + li];
        float wa = __uint_as_float((unsigned int)((unsigned long long)qa >> 32));
        float wb = __uint_as_float((unsigned int)((unsigned long long)qb >> 32));
        s0 = fmaf(wa, bflo(va.x), s0); s1 = fmaf(wa, bfhi(va.x), s1);
        s2 = fmaf(wa, bflo(va.y), s2); s3 = fmaf(wa, bfhi(va.y), s3);
        s4 = fmaf(wa, bflo(va.z), s4); s5 = fmaf(wa, bfhi(va.z), s5);
        s6 = fmaf(wa, bflo(va.w), s6); s7 = fmaf(wa, bfhi(va.w), s7);
        s0 = fmaf(wb, bflo(vb.x), s0); s1 = fmaf(wb, bfhi(vb.x), s1);
        s2 = fmaf(wb, bflo(vb.y), s2); s3 = fmaf(wb, bfhi(vb.y), s3);
        s4 = fmaf(wb, bflo(vb.z), s4); s5 = fmaf(wb, bfhi(vb.z), s5);
        s6 = fmaf(wb, bflo(vb.w), s6); s7 = fmaf(wb, bfhi(vb.w), s7);
    }
    for (; e < end; e += 4) {
        long long qa = pack[e];
        uint4 va = tin4[(size_t)(unsigned int)qa * 16 + li];
        float wa = __uint_as_float((unsigned int)((unsigned long long)qa >> 32));
        s0 = fmaf(wa, bflo(va.x), s0); s1 = fmaf(wa, bfhi(va.x), s1);
        s2 = fmaf(wa, bflo(va.y), s2); s3 = fmaf(wa, bfhi(va.y), s3);
        s4 = fmaf(wa, bflo(va.z), s4); s5 = fmaf(wa, bfhi(va.z), s5);
        s6 = fmaf(wa, bflo(va.w), s6); s7 = fmaf(wa, bfhi(va.w), s7);
    }
    // reduce across the 4 groups (lanes with equal li)
    s0 += __shfl_xor(s0, 16); s1 += __shfl_xor(s1, 16);
    s2 += __shfl_xor(s2, 16); s3 += __shfl_xor(s3, 16);
    s4 += __shfl_xor(s4, 16); s5 += __shfl_xor(s5, 16);
    s6 += __shfl_xor(s6, 16); s7 += __shfl_xor(s7, 16);
    s0 += __shfl_xor(s0, 32); s1 += __shfl_xor(s1, 32);
    s2 += __shfl_xor(s2, 32); s3 += __shfl_xor(s3, 32);
    s4 += __shfl_xor(s4, 32); s5 += __shfl_xor(s5, 32);
    s6 += __shfl_xor(s6, 32); s7 += __shfl_xor(s7, 32);
    if (lane < 16) {
        float r0 = s0, r1 = s1, r2 = s2, r3 = s3, r4 = s4, r5 = s5, r6 = s6, r7 = s7;
        if (MODE != 2) {
            uint4 zv = z4[(size_t)node * 16 + li];
            r0 += bflo(zv.x); r1 += bfhi(zv.x); r2 += bflo(zv.y); r3 += bfhi(zv.y);
            r4 += bflo(zv.z); r5 += bfhi(zv.z); r6 += bflo(zv.w); r7 += bfhi(zv.w);
        }
        if (MODE == 1) {
            const float* bp = bias + li * 8;
            r0 = fmaxf(r0 + bp[0], 0.f); r1 = fmaxf(r1 + bp[1], 0.f);
            r2 = fmaxf(r2 + bp[2], 0.f); r3 = fmaxf(r3 + bp[3], 0.f);
            r4 = fmaxf(r4 + bp[4], 0.f); r5 = fmaxf(r5 + bp[5], 0.f);
            r6 = fmaxf(r6 + bp[6], 0.f); r7 = fmaxf(r7 + bp[7], 0.f);
        }
        uint4 o;
        o.x = (unsigned int)f2bf(r0) | ((unsigned int)f2bf(r1) << 16);
        o.y = (unsigned int)f2bf(r2) | ((unsigned int)f2bf(r3) << 16);
        o.z = (unsigned int)f2bf(r4) | ((unsigned int)f2bf(r5) << 16);
        o.w = (unsigned int)f2bf(r6) | ((unsigned int)f2bf(r7) << 16);
        tout4[(size_t)node * 16 + li] = o;
    }
}

// ---------------- launch ----------------

extern "C" void kernel_launch(void* const* d_in, const int* in_sizes, int n_in,
                              void* d_out, int out_size, void* d_ws, size_t ws_size,
                              hipStream_t stream) {
    const float* x   = (const float*)d_in[0];
    const int*   ei  = (const int*)d_in[1];
    const float* pe  = (const float*)d_in[2];
    const float* ew  = (const float*)d_in[3];
    const float* W0  = (const float*)d_in[4];
    const float* b0  = (const float*)d_in[5];
    const float* W1  = (const float*)d_in[6];
    const float* b1  = (const float*)d_in[7];
    const float* Wmu = (const float*)d_in[8];
    const float* bmu = (const float*)d_in[9];
    const float* Wlv = (const float*)d_in[10];
    const float* blv = (const float*)d_in[11];

    const int N = in_sizes[0] / 128;
    const int E = in_sizes[3];
    const int* src = ei;
    const int* dst = ei + E;

    char* ws = (char*)d_ws;
    size_t off = 0;
    auto alloc = [&](size_t bytes) {
        size_t o = off;
        off += (bytes + 1023) & ~(size_t)1023;
        return o;
    };
    float* deg = (float*)(ws + alloc(4 * (size_t)N));   // becomes dis in-place
    int* cnt   = (int*)(ws + alloc(4 * (size_t)N));
    size_t zero_bytes = off;                            // memset deg+cnt
    unsigned char* rank = (unsigned char*)(ws + alloc((size_t)E));
    int* rowp  = (int*)(ws + alloc(4 * (size_t)N));
    int* bsum  = (int*)(ws + alloc(4 * 128));
    unsigned short* AT0 = (unsigned short*)(ws + alloc(2 * 4 * 128 * 160));
    unsigned short* AT1 = (unsigned short*)(ws + alloc(2 * 4 * 128 * 128));
    unsigned short* ATH = (unsigned short*)(ws + alloc(2 * 128 * 128));
    int2* pack = (int2*)(ws + alloc(8 * (size_t)E));
    unsigned int* B1 = (unsigned int*)(ws + alloc(2 * (size_t)N * 128));
    unsigned int* B2 = (unsigned int*)(ws + alloc(2 * (size_t)N * 128));
    unsigned int* B3 = (unsigned int*)(ws + alloc(2 * (size_t)N * 128));
    unsigned int* B4 = (unsigned int*)(ws + alloc(2 * (size_t)N * 128));
    unsigned int* B5 = (unsigned int*)(ws + alloc(2 * (size_t)N * 128));

    hipMemsetAsync(ws, 0, zero_bytes, stream);

    dim3 b256(256);
    // fused weight prep (AT0 | AT1 | ATH)
    {
        int tot = 4 * 128 * 160 + 4 * 128 * 128 + 128 * 128;
        k_prep_weights<<<dim3((tot + 255) / 256), b256, 0, stream>>>(W0, W1, Wmu, Wlv, AT0, AT1, ATH);
    }

    // K1: layer-0 pair-GEMM tiles + tail atomics
    int G64 = (N + 63) / 64;
    int total = 2 * G64;
    int EPC = (E + total - 1) / total;
    k_mega<<<dim3(total), b256, 0, stream>>>(src, dst, ew, deg, cnt, rank, x, pe, AT0,
                                             (unsigned short*)B1, (unsigned short*)B2,
                                             (unsigned short*)B3, (unsigned short*)B4,
                                             N, E, EPC);

    int nb = (N + 1023) / 1024;
    k_dis_blocksum<<<dim3(nb), dim3(1024), 0, stream>>>(deg, cnt, bsum, N);
    k_scan_bsum<<<dim3(1), dim3(128), 0, stream>>>(bsum, nb);
    k_scan<<<dim3(nb), dim3(1024), 0, stream>>>(cnt, bsum, rowp, N);
    k_build_csr<<<dim3((E + 1023) / 1024), b256, 0, stream>>>(src, dst, ew, deg, rowp, rank, pack, E);

    dim3 gp((N + 3) / 4);
    const long long* packll = (const long long*)pack;
    uint4* B1v = (uint4*)B1; uint4* B2v = (uint4*)B2; uint4* B3v = (uint4*)B3;
    uint4* B4v = (uint4*)B4; uint4* B5v = (uint4*)B5;

    // layer 0 (Horner): B1=Z3 B2=Z2 B3=Z1 B4=Z0 (from K1)
    k_prop<0><<<gp, b256, 0, stream>>>(B1v, B2v, B5v, nullptr, rowp, packll, N, E);   // B5 = Z2 + P Z3
    k_prop<0><<<gp, b256, 0, stream>>>(B5v, B3v, B1v, nullptr, rowp, packll, N, E);   // B1 = Z1 + P B5
    k_prop<1><<<gp, b256, 0, stream>>>(B1v, B4v, B2v, b0, rowp, packll, N, E);        // B2 = h1

    // layer 1 (powers form): U1 = P h1, U2 = P U1, U3 = P U2
    k_prop<2><<<gp, b256, 0, stream>>>(B2v, nullptr, B3v, nullptr, rowp, packll, N, E);  // B3 = U1
    k_prop<2><<<gp, b256, 0, stream>>>(B3v, nullptr, B4v, nullptr, rowp, packll, N, E);  // B4 = U2
    k_prop<2><<<gp, b256, 0, stream>>>(B4v, nullptr, B5v, nullptr, rowp, packll, N, E);  // B5 = U3

    // fused: h2 = relu([h1|U1|U2|U3]@AT1 + b1) -> heads -> d_out
    k_gemm_l1_heads<<<dim3(G64), b256, 0, stream>>>((const unsigned short*)B2, (const unsigned short*)B3,
                                                    (const unsigned short*)B4, (const unsigned short*)B5,
                                                    AT1, ATH, b1, bmu, blv, (float*)d_out, N);
}

// Round 12
// 686.936 us; speedup vs baseline: 1.1205x; 1.0123x over previous
//
#include <hip/hip_runtime.h>
#include <hip/hip_bf16.h>

typedef float f32x4 __attribute__((ext_vector_type(4)));
typedef unsigned short u16x8 __attribute__((ext_vector_type(8)));

static __device__ __forceinline__ void mfma16(f32x4& c, const u16x8& a, const u16x8& b) {
    asm("v_mfma_f32_16x16x32_bf16 %0, %1, %2, %0" : "+v"(c) : "v"(a), "v"(b));
}

static __device__ __forceinline__ unsigned short f2bf(float f) {
    __hip_bfloat16 h = __float2bfloat16(f);
    return *reinterpret_cast<unsigned short*>(&h);
}

static __device__ __forceinline__ float bflo(unsigned int v) { return __uint_as_float(v << 16); }
static __device__ __forceinline__ float bfhi(unsigned int v) { return __uint_as_float(v & 0xffff0000u); }

// ---------------- small prep kernels ----------------

__global__ __launch_bounds__(1024) void k_dis_blocksum(float* deg, const int* __restrict__ cnt,
                                                       int* bsum, int N) {
    __shared__ int sd[1024];
    int i = blockIdx.x * 1024 + threadIdx.x;
    if (i < N) {
        float d = deg[i];
        deg[i] = (d > 0.f) ? rsqrtf(d) : 0.f;
    }
    sd[threadIdx.x] = (i < N) ? cnt[i] : 0;
    __syncthreads();
    for (int s = 512; s > 0; s >>= 1) {
        if (threadIdx.x < s) sd[threadIdx.x] += sd[threadIdx.x + s];
        __syncthreads();
    }
    if (threadIdx.x == 0) bsum[blockIdx.x] = sd[0];
}

__global__ __launch_bounds__(128) void k_scan_bsum(int* bsum, int nb) {
    __shared__ int sd[128];
    int t = threadIdx.x;
    int v = (t < nb) ? bsum[t] : 0;
    sd[t] = v;
    __syncthreads();
    for (int d = 1; d < 128; d <<= 1) {
        int x = (t >= d) ? sd[t - d] : 0;
        __syncthreads();
        sd[t] += x;
        __syncthreads();
    }
    if (t < nb) bsum[t] = sd[t] - v;  // exclusive block offsets
}

__global__ __launch_bounds__(1024) void k_scan(const int* __restrict__ cnt, const int* __restrict__ bsum,
                                               int* rowp, int N) {
    __shared__ int sd[1024];
    int i = blockIdx.x * 1024 + threadIdx.x;
    int v = (i < N) ? cnt[i] : 0;
    sd[threadIdx.x] = v;
    __syncthreads();
    for (int d = 1; d < 1024; d <<= 1) {
        int x = (threadIdx.x >= d) ? sd[threadIdx.x - d] : 0;
        __syncthreads();
        sd[threadIdx.x] += x;
        __syncthreads();
    }
    if (i < N) rowp[i] = sd[threadIdx.x] - v + bsum[blockIdx.x];
}

// atomic-free CSR fill: pos = rowp[dst] + rank (u8), unroll 4 for scatter MLP
__global__ __launch_bounds__(256) void k_build_csr(const int* __restrict__ src, const int* __restrict__ dst,
                                                   const float* __restrict__ ew, const float* __restrict__ dis,
                                                   const int* __restrict__ rowp,
                                                   const unsigned char* __restrict__ rank,
                                                   int2* __restrict__ pack, int E) {
    int base = blockIdx.x * 1024 + threadIdx.x;
#pragma unroll
    for (int u = 0; u < 4; u++) {
        int e = base + u * 256;
        if (e < E) {
            int s = src[e], d = dst[e];
            float w = (s == d) ? 0.f : ew[e];
            float wh = -dis[s] * w * dis[d];
            int pos = rowp[d] + (int)rank[e];
            int2 p;
            p.x = s;
            p.y = __float_as_int(wh);
            pack[pos] = p;
        }
    }
}

// ---------------- weight prep (fused: AT0 | AT1 | ATH) ----------------
// AT[sel][n][kk] = A_sel[kk][n] (transposed, bf16), A0=W0-W2, A1=W1-3W3, A2=2W2, A3=4W3

static __device__ __forceinline__ void combine_elem(const float* __restrict__ W,
                                                    unsigned short* __restrict__ AT,
                                                    int i, int D, int KPAD) {
    int sel = i / (128 * KPAD);
    int rem = i - sel * 128 * KPAD;
    int n = rem / KPAD;
    int kk = rem - n * KPAD;
    float v = 0.f;
    if (kk < D) {
        if (sel == 0)      v = W[(0 * D + kk) * 128 + n] - W[(2 * D + kk) * 128 + n];
        else if (sel == 1) v = W[(1 * D + kk) * 128 + n] - 3.f * W[(3 * D + kk) * 128 + n];
        else if (sel == 2) v = 2.f * W[(2 * D + kk) * 128 + n];
        else               v = 4.f * W[(3 * D + kk) * 128 + n];
    }
    AT[i] = f2bf(v);
}

__global__ __launch_bounds__(256) void k_prep_weights(const float* __restrict__ W0,
                                                      const float* __restrict__ W1,
                                                      const float* __restrict__ Wmu,
                                                      const float* __restrict__ Wlv,
                                                      unsigned short* __restrict__ AT0,
                                                      unsigned short* __restrict__ AT1,
                                                      unsigned short* __restrict__ ATH) {
    constexpr int T0 = 4 * 128 * 160;
    constexpr int T1 = 4 * 128 * 128;
    int i = blockIdx.x * 256 + threadIdx.x;
    if (i < T0) {
        combine_elem(W0, AT0, i, 144, 160);
    } else if (i < T0 + T1) {
        combine_elem(W1, AT1, i - T0, 128, 128);
    } else if (i < T0 + T1 + 128 * 128) {
        int j = i - T0 - T1;
        int n = j >> 7, kk = j & 127;
        float v = (n < 64) ? Wmu[kk * 64 + n] : Wlv[kk * 64 + (n - 64)];
        ATH[j] = f2bf(v);
    }
}

// ---------------- reg-B pair GEMM body (mega layer-0): BM=64, BN=128, 2 weights/block ----------------

template <int KPAD>
static __device__ __forceinline__ void gemm_pair_regB(const float* __restrict__ x,
                                                      const float* __restrict__ pe,
                                                      const unsigned short* __restrict__ Bta,
                                                      const unsigned short* __restrict__ Btb,
                                                      unsigned short* __restrict__ outA,
                                                      unsigned short* __restrict__ outB,
                                                      int N, int bx, unsigned short* As) {
    constexpr int LP = KPAD + 8;
    const int tid = threadIdx.x;
    const int row0 = bx * 64;

    {   // stage A tile (64 x KPAD) = concat(x, pe, pad) -> bf16
        constexpr int TOT = 64 * KPAD;
        for (int c = tid * 8; c < TOT; c += 256 * 8) {
            int r = c / KPAD;
            int k = c - r * KPAD;
            int gr = row0 + r;
            if (gr > N - 1) gr = N - 1;
            u16x8 v;
            if (k < 128) {
                float4 f0 = *reinterpret_cast<const float4*>(&x[(size_t)gr * 128 + k]);
                float4 f1 = *reinterpret_cast<const float4*>(&x[(size_t)gr * 128 + k + 4]);
                v[0] = f2bf(f0.x); v[1] = f2bf(f0.y); v[2] = f2bf(f0.z); v[3] = f2bf(f0.w);
                v[4] = f2bf(f1.x); v[5] = f2bf(f1.y); v[6] = f2bf(f1.z); v[7] = f2bf(f1.w);
            } else if (k < 144) {
                float4 f0 = *reinterpret_cast<const float4*>(&pe[(size_t)gr * 16 + (k - 128)]);
                float4 f1 = *reinterpret_cast<const float4*>(&pe[(size_t)gr * 16 + (k - 124)]);
                v[0] = f2bf(f0.x); v[1] = f2bf(f0.y); v[2] = f2bf(f0.z); v[3] = f2bf(f0.w);
                v[4] = f2bf(f1.x); v[5] = f2bf(f1.y); v[6] = f2bf(f1.z); v[7] = f2bf(f1.w);
            } else {
                v = (u16x8){0, 0, 0, 0, 0, 0, 0, 0};
            }
            *reinterpret_cast<u16x8*>(&As[r * LP + k]) = v;
        }
    }
    __syncthreads();

    const int wave = tid >> 6, lane = tid & 63;
    const int wm = wave & 1, ww = wave >> 1;
    const int lr = lane & 15, lg = lane >> 4;
    const unsigned short* Bw = ww ? Btb : Bta;

    f32x4 acc[2][8];
#pragma unroll
    for (int i = 0; i < 2; i++)
#pragma unroll
        for (int j = 0; j < 8; j++) acc[i][j] = (f32x4){0.f, 0.f, 0.f, 0.f};

    asm volatile("s_nop 7"
                 : "+v"(acc[0][0]), "+v"(acc[0][4]), "+v"(acc[1][0]), "+v"(acc[1][4]));

    constexpr int KS = KPAD / 32;
#pragma unroll
    for (int ks = 0; ks < KS; ks++) {
        u16x8 a0 = *reinterpret_cast<const u16x8*>(&As[(wm * 32 + lr) * LP + ks * 32 + lg * 8]);
        u16x8 a1 = *reinterpret_cast<const u16x8*>(&As[(wm * 32 + 16 + lr) * LP + ks * 32 + lg * 8]);
#pragma unroll
        for (int g = 0; g < 2; g++) {
            u16x8 b[4];
#pragma unroll
            for (int j = 0; j < 4; j++)
                b[j] = *reinterpret_cast<const u16x8*>(&Bw[(size_t)((g * 4 + j) * 16 + lr) * KPAD + ks * 32 + lg * 8]);
#pragma unroll
            for (int j = 0; j < 4; j++) {
                mfma16(acc[0][g * 4 + j], a0, b[j]);
                mfma16(acc[1][g * 4 + j], a1, b[j]);
            }
        }
    }

    asm volatile("s_nop 7\n\ts_nop 7\n\ts_nop 7"
                 : "+v"(acc[0][0]), "+v"(acc[0][4]), "+v"(acc[1][0]), "+v"(acc[1][4]));

    unsigned short* outp = ww ? outB : outA;
#pragma unroll
    for (int fm = 0; fm < 2; fm++)
#pragma unroll
        for (int fn = 0; fn < 8; fn++)
#pragma unroll
            for (int i = 0; i < 4; i++) {
                int r = row0 + wm * 32 + fm * 16 + lg * 4 + i;
                if (r < N) outp[(size_t)r * 128 + fn * 16 + lr] = f2bf(acc[fm][fn][i]);
            }
}

// ---------------- K1 mega: {layer-0 pair-GEMM tile, fused concat} then {deg FF + cnt/rank atomics} ----------------

__global__ __launch_bounds__(256, 4) void k_mega(const int* __restrict__ src, const int* __restrict__ dst,
                                                 const float* __restrict__ ew,
                                                 float* deg, int* cnt, unsigned char* __restrict__ rank,
                                                 const float* __restrict__ x, const float* __restrict__ pe,
                                                 const unsigned short* __restrict__ AT0,
                                                 unsigned short* __restrict__ oZ3, unsigned short* __restrict__ oZ2,
                                                 unsigned short* __restrict__ oZ1, unsigned short* __restrict__ oZ0,
                                                 int N, int E, int EPC) {
    __shared__ __align__(16) unsigned short As[64 * 168];
    const int bid = blockIdx.x;

    {
        int P = bid & 1;
        int bx = bid >> 1;
        const unsigned short* Bta = AT0 + (size_t)(3 - 2 * P) * 128 * 160;
        const unsigned short* Btb = AT0 + (size_t)(2 - 2 * P) * 128 * 160;
        unsigned short* outA = (P == 0) ? oZ3 : oZ1;
        unsigned short* outB = (P == 0) ? oZ2 : oZ0;
        gemm_pair_regB<160>(x, pe, Bta, Btb, outA, outB, N, bx, As);
    }

    {
        int e0 = bid * EPC;
        int e1 = e0 + EPC;
        if (e1 > E) e1 = E;
        for (int e = e0 + threadIdx.x; e < e1; e += 256) {
            int s = src[e], d = dst[e];
            float w = (s == d) ? 0.f : ew[e];
            atomicAdd(&deg[s], w);
            rank[e] = (unsigned char)atomicAdd(&cnt[d], 1);
        }
    }
}

// ---------------- fused layer-1 GEMM (K=512 powers form) + heads ----------------
// h2 = relu([h1|U1|U2|U3] @ [A0;A1;A2;A3] + b1)  (h2 kept in LDS), then [mu|lv] = h2 @ ATH^T + bias.

__global__ __launch_bounds__(256, 4) void k_gemm_l1_heads(const unsigned short* __restrict__ h1,
                                                          const unsigned short* __restrict__ U1,
                                                          const unsigned short* __restrict__ U2,
                                                          const unsigned short* __restrict__ U3,
                                                          const unsigned short* __restrict__ AT1,
                                                          const unsigned short* __restrict__ ATH,
                                                          const float* __restrict__ b1,
                                                          const float* __restrict__ bmu,
                                                          const float* __restrict__ blv,
                                                          float* __restrict__ out, int N) {
    constexpr int LP = 136;
    __shared__ __align__(16) unsigned short As[64 * LP];
    const int tid = threadIdx.x;
    const int row0 = blockIdx.x * 64;
    const int wave = tid >> 6, lane = tid & 63;
    const int wm = wave & 1, wn = wave >> 1;
    const int lr = lane & 15, lg = lane >> 4;

    f32x4 acc[2][4];
#pragma unroll
    for (int i = 0; i < 2; i++)
#pragma unroll
        for (int j = 0; j < 4; j++) acc[i][j] = (f32x4){0.f, 0.f, 0.f, 0.f};

#pragma unroll 4
    for (int seg = 0; seg < 4; seg++) {
        const unsigned short* sp = (seg == 0) ? h1 : (seg == 1) ? U1 : (seg == 2) ? U2 : U3;
        for (int c = tid * 8; c < 64 * 128; c += 256 * 8) {
            int r = c >> 7;
            int k = c & 127;
            int gr = row0 + r;
            if (gr > N - 1) gr = N - 1;
            u16x8 v = *reinterpret_cast<const u16x8*>(&sp[(size_t)gr * 128 + k]);
            *reinterpret_cast<u16x8*>(&As[r * LP + k]) = v;
        }
        __syncthreads();
        const unsigned short* Bseg = AT1 + (size_t)seg * 128 * 128;
#pragma unroll
        for (int ks = 0; ks < 4; ks++) {
            u16x8 a0 = *reinterpret_cast<const u16x8*>(&As[(wm * 32 + lr) * LP + ks * 32 + lg * 8]);
            u16x8 a1 = *reinterpret_cast<const u16x8*>(&As[(wm * 32 + 16 + lr) * LP + ks * 32 + lg * 8]);
            u16x8 b[4];
#pragma unroll
            for (int j = 0; j < 4; j++)
                b[j] = *reinterpret_cast<const u16x8*>(&Bseg[(size_t)((wn * 64 + j * 16 + lr)) * 128 + ks * 32 + lg * 8]);
#pragma unroll
            for (int j = 0; j < 4; j++) {
                mfma16(acc[0][j], a0, b[j]);
                mfma16(acc[1][j], a1, b[j]);
            }
        }
        __syncthreads();  // protect As before next stage overwrites
    }

    asm volatile("s_nop 7\n\ts_nop 7\n\ts_nop 7"
                 : "+v"(acc[0][0]), "+v"(acc[0][1]), "+v"(acc[0][2]), "+v"(acc[0][3]),
                   "+v"(acc[1][0]), "+v"(acc[1][1]), "+v"(acc[1][2]), "+v"(acc[1][3]));

#pragma unroll
    for (int fm = 0; fm < 2; fm++)
#pragma unroll
        for (int fn = 0; fn < 4; fn++)
#pragma unroll
            for (int i = 0; i < 4; i++) {
                int rl = wm * 32 + fm * 16 + lg * 4 + i;
                int c = wn * 64 + fn * 16 + lr;
                float v = fmaxf(acc[fm][fn][i] + b1[c], 0.f);
                As[rl * LP + c] = f2bf(v);
            }
    __syncthreads();

    // heads: [mu|lv] = h2(LDS) @ ATH^T, K=128
    f32x4 acc2[2][4];
#pragma unroll
    for (int i = 0; i < 2; i++)
#pragma unroll
        for (int j = 0; j < 4; j++) acc2[i][j] = (f32x4){0.f, 0.f, 0.f, 0.f};

    asm volatile("s_nop 7"
                 : "+v"(acc2[0][0]), "+v"(acc2[0][1]), "+v"(acc2[1][0]), "+v"(acc2[1][1]));

#pragma unroll
    for (int ks = 0; ks < 4; ks++) {
        u16x8 a0 = *reinterpret_cast<const u16x8*>(&As[(wm * 32 + lr) * LP + ks * 32 + lg * 8]);
        u16x8 a1 = *reinterpret_cast<const u16x8*>(&As[(wm * 32 + 16 + lr) * LP + ks * 32 + lg * 8]);
        u16x8 b[4];
#pragma unroll
        for (int j = 0; j < 4; j++)
            b[j] = *reinterpret_cast<const u16x8*>(&ATH[(size_t)(wn * 64 + j * 16 + lr) * 128 + ks * 32 + lg * 8]);
#pragma unroll
        for (int j = 0; j < 4; j++) {
            mfma16(acc2[0][j], a0, b[j]);
            mfma16(acc2[1][j], a1, b[j]);
        }
    }

    asm volatile("s_nop 7\n\ts_nop 7\n\ts_nop 7"
                 : "+v"(acc2[0][0]), "+v"(acc2[0][1]), "+v"(acc2[1][0]), "+v"(acc2[1][1]));

#pragma unroll
    for (int fm = 0; fm < 2; fm++)
#pragma unroll
        for (int fn = 0; fn < 4; fn++)
#pragma unroll
            for (int i = 0; i < 4; i++) {
                int r = row0 + wm * 32 + fm * 16 + lg * 4 + i;
                if (r < N) {
                    int c = wn * 64 + fn * 16 + lr;
                    if (c < 64) out[(size_t)r * 64 + c] = acc2[fm][fn][i] + bmu[c];
                    else out[(size_t)N * 64 + (size_t)r * 64 + (c - 64)] = acc2[fm][fn][i] + blv[c - 64];
                }
            }
}

// ---------------- sparse prop v5: quarter-wave split, unroll-4 (covers full typical degree) ----------------
// 4 groups of 16 lanes; group g handles CSR slots e = beg+g, +4, ... ; lane loads uint4 (16B)
// so 16 lanes cover one full 256B row. Unroll-4 = 4 independent pack loads + 4 independent gathers
// in flight per iteration (deg=16 -> exactly one iteration, no tail). Cross-group reduce: shfl_xor 16,32.

template <int MODE>  // 0: z + P t ; 1: relu(z + P t + bias) ; 2: pure P t
__global__ __launch_bounds__(256) void k_prop(const uint4* __restrict__ tin4,
                                              const uint4* __restrict__ z4,
                                              uint4* __restrict__ tout4,
                                              const float* __restrict__ bias,
                                              const int* __restrict__ rowp,
                                              const long long* __restrict__ pack,
                                              int N, int E) {
    int wave = threadIdx.x >> 6, lane = threadIdx.x & 63;
    int node = blockIdx.x * 4 + wave;
    if (node >= N) return;
    int beg = rowp[node];
    int end = (node == N - 1) ? E : rowp[node + 1];
    const int grp = lane >> 4, li = lane & 15;
    float s0 = 0.f, s1 = 0.f, s2 = 0.f, s3 = 0.f, s4 = 0.f, s5 = 0.f, s6 = 0.f, s7 = 0.f;
    int e = beg + grp;
    for (; e + 12 < end; e += 16) {
        long long qa = pack[e];
        long long qb = pack[e + 4];
        long long qc = pack[e + 8];
        long long qd = pack[e + 12];
        uint4 va = tin4[(size_t)(unsigned int)qa * 16 + li];
        uint4 vb = tin4[(size_t)(unsigned int)qb * 16 + li];
        uint4 vc = tin4[(size_t)(unsigned int)qc * 16 + li];
        uint4 vd = tin4[(size_t)(unsigned int)qd * 16 + li];
        float wa = __uint_as_float((unsigned int)((unsigned long long)qa >> 32));
        float wb = __uint_as_float((unsigned int)((unsigned long long)qb >> 32));
        float wc = __uint_as_float((unsigned int)((unsigned long long)qc >> 32));
        float wd = __uint_as_float((unsigned int)((unsigned long long)qd >> 32));
        s0 = fmaf(wa, bflo(va.x), s0); s1 = fmaf(wa, bfhi(va.x), s1);
        s2 = fmaf(wa, bflo(va.y), s2); s3 = fmaf(wa, bfhi(va.y), s3);
        s4 = fmaf(wa, bflo(va.z), s4); s5 = fmaf(wa, bfhi(va.z), s5);
        s6 = fmaf(wa, bflo(va.w), s6); s7 = fmaf(wa, bfhi(va.w), s7);
        s0 = fmaf(wb, bflo(vb.x), s0); s1 = fmaf(wb, bfhi(vb.x), s1);
        s2 = fmaf(wb, bflo(vb.y), s2); s3 = fmaf(wb, bfhi(vb.y), s3);
        s4 = fmaf(wb, bflo(vb.z), s4); s5 = fmaf(wb, bfhi(vb.z), s5);
        s6 = fmaf(wb, bflo(vb.w), s6); s7 = fmaf(wb, bfhi(vb.w), s7);
        s0 = fmaf(wc, bflo(vc.x), s0); s1 = fmaf(wc, bfhi(vc.x), s1);
        s2 = fmaf(wc, bflo(vc.y), s2); s3 = fmaf(wc, bfhi(vc.y), s3);
        s4 = fmaf(wc, bflo(vc.z), s4); s5 = fmaf(wc, bfhi(vc.z), s5);
        s6 = fmaf(wc, bflo(vc.w), s6); s7 = fmaf(wc, bfhi(vc.w), s7);
        s0 = fmaf(wd, bflo(vd.x), s0); s1 = fmaf(wd, bfhi(vd.x), s1);
        s2 = fmaf(wd, bflo(vd.y), s2); s3 = fmaf(wd, bfhi(vd.y), s3);
        s4 = fmaf(wd, bflo(vd.z), s4); s5 = fmaf(wd, bfhi(vd.z), s5);
        s6 = fmaf(wd, bflo(vd.w), s6); s7 = fmaf(wd, bfhi(vd.w), s7);
    }
    if (e + 4 < end) {
        long long qa = pack[e];
        long long qb = pack[e + 4];
        uint4 va = tin4[(size_t)(unsigned int)qa * 16 + li];
        uint4 vb = tin4[(size_t)(unsigned int)qb * 16 + li];
        float wa = __uint_as_float((unsigned int)((unsigned long long)qa >> 32));
        float wb = __uint_as_float((unsigned int)((unsigned long long)qb >> 32));
        s0 = fmaf(wa, bflo(va.x), s0); s1 = fmaf(wa, bfhi(va.x), s1);
        s2 = fmaf(wa, bflo(va.y), s2); s3 = fmaf(wa, bfhi(va.y), s3);
        s4 = fmaf(wa, bflo(va.z), s4); s5 = fmaf(wa, bfhi(va.z), s5);
        s6 = fmaf(wa, bflo(va.w), s6); s7 = fmaf(wa, bfhi(va.w), s7);
        s0 = fmaf(wb, bflo(vb.x), s0); s1 = fmaf(wb, bfhi(vb.x), s1);
        s2 = fmaf(wb, bflo(vb.y), s2); s3 = fmaf(wb, bfhi(vb.y), s3);
        s4 = fmaf(wb, bflo(vb.z), s4); s5 = fmaf(wb, bfhi(vb.z), s5);
        s6 = fmaf(wb, bflo(vb.w), s6); s7 = fmaf(wb, bfhi(vb.w), s7);
        e += 8;
    }
    for (; e < end; e += 4) {
        long long qa = pack[e];
        uint4 va = tin4[(size_t)(unsigned int)qa * 16 + li];
        float wa = __uint_as_float((unsigned int)((unsigned long long)qa >> 32));
        s0 = fmaf(wa, bflo(va.x), s0); s1 = fmaf(wa, bfhi(va.x), s1);
        s2 = fmaf(wa, bflo(va.y), s2); s3 = fmaf(wa, bfhi(va.y), s3);
        s4 = fmaf(wa, bflo(va.z), s4); s5 = fmaf(wa, bfhi(va.z), s5);
        s6 = fmaf(wa, bflo(va.w), s6); s7 = fmaf(wa, bfhi(va.w), s7);
    }
    // reduce across the 4 groups (lanes with equal li)
    s0 += __shfl_xor(s0, 16); s1 += __shfl_xor(s1, 16);
    s2 += __shfl_xor(s2, 16); s3 += __shfl_xor(s3, 16);
    s4 += __shfl_xor(s4, 16); s5 += __shfl_xor(s5, 16);
    s6 += __shfl_xor(s6, 16); s7 += __shfl_xor(s7, 16);
    s0 += __shfl_xor(s0, 32); s1 += __shfl_xor(s1, 32);
    s2 += __shfl_xor(s2, 32); s3 += __shfl_xor(s3, 32);
    s4 += __shfl_xor(s4, 32); s5 += __shfl_xor(s5, 32);
    s6 += __shfl_xor(s6, 32); s7 += __shfl_xor(s7, 32);
    if (lane < 16) {
        float r0 = s0, r1 = s1, r2 = s2, r3 = s3, r4 = s4, r5 = s5, r6 = s6, r7 = s7;
        if (MODE != 2) {
            uint4 zv = z4[(size_t)node * 16 + li];
            r0 += bflo(zv.x); r1 += bfhi(zv.x); r2 += bflo(zv.y); r3 += bfhi(zv.y);
            r4 += bflo(zv.z); r5 += bfhi(zv.z); r6 += bflo(zv.w); r7 += bfhi(zv.w);
        }
        if (MODE == 1) {
            const float* bp = bias + li * 8;
            r0 = fmaxf(r0 + bp[0], 0.f); r1 = fmaxf(r1 + bp[1], 0.f);
            r2 = fmaxf(r2 + bp[2], 0.f); r3 = fmaxf(r3 + bp[3], 0.f);
            r4 = fmaxf(r4 + bp[4], 0.f); r5 = fmaxf(r5 + bp[5], 0.f);
            r6 = fmaxf(r6 + bp[6], 0.f); r7 = fmaxf(r7 + bp[7], 0.f);
        }
        uint4 o;
        o.x = (unsigned int)f2bf(r0) | ((unsigned int)f2bf(r1) << 16);
        o.y = (unsigned int)f2bf(r2) | ((unsigned int)f2bf(r3) << 16);
        o.z = (unsigned int)f2bf(r4) | ((unsigned int)f2bf(r5) << 16);
        o.w = (unsigned int)f2bf(r6) | ((unsigned int)f2bf(r7) << 16);
        tout4[(size_t)node * 16 + li] = o;
    }
}

// ---------------- launch ----------------

extern "C" void kernel_launch(void* const* d_in, const int* in_sizes, int n_in,
                              void* d_out, int out_size, void* d_ws, size_t ws_size,
                              hipStream_t stream) {
    const float* x   = (const float*)d_in[0];
    const int*   ei  = (const int*)d_in[1];
    const float* pe  = (const float*)d_in[2];
    const float* ew  = (const float*)d_in[3];
    const float* W0  = (const float*)d_in[4];
    const float* b0  = (const float*)d_in[5];
    const float* W1  = (const float*)d_in[6];
    const float* b1  = (const float*)d_in[7];
    const float* Wmu = (const float*)d_in[8];
    const float* bmu = (const float*)d_in[9];
    const float* Wlv = (const float*)d_in[10];
    const float* blv = (const float*)d_in[11];

    const int N = in_sizes[0] / 128;
    const int E = in_sizes[3];
    const int* src = ei;
    const int* dst = ei + E;

    char* ws = (char*)d_ws;
    size_t off = 0;
    auto alloc = [&](size_t bytes) {
        size_t o = off;
        off += (bytes + 1023) & ~(size_t)1023;
        return o;
    };
    float* deg = (float*)(ws + alloc(4 * (size_t)N));   // becomes dis in-place
    int* cnt   = (int*)(ws + alloc(4 * (size_t)N));
    size_t zero_bytes = off;                            // memset deg+cnt
    unsigned char* rank = (unsigned char*)(ws + alloc((size_t)E));
    int* rowp  = (int*)(ws + alloc(4 * (size_t)N));
    int* bsum  = (int*)(ws + alloc(4 * 128));
    unsigned short* AT0 = (unsigned short*)(ws + alloc(2 * 4 * 128 * 160));
    unsigned short* AT1 = (unsigned short*)(ws + alloc(2 * 4 * 128 * 128));
    unsigned short* ATH = (unsigned short*)(ws + alloc(2 * 128 * 128));
    int2* pack = (int2*)(ws + alloc(8 * (size_t)E));
    unsigned int* B1 = (unsigned int*)(ws + alloc(2 * (size_t)N * 128));
    unsigned int* B2 = (unsigned int*)(ws + alloc(2 * (size_t)N * 128));
    unsigned int* B3 = (unsigned int*)(ws + alloc(2 * (size_t)N * 128));
    unsigned int* B4 = (unsigned int*)(ws + alloc(2 * (size_t)N * 128));
    unsigned int* B5 = (unsigned int*)(ws + alloc(2 * (size_t)N * 128));

    hipMemsetAsync(ws, 0, zero_bytes, stream);

    dim3 b256(256);
    // fused weight prep (AT0 | AT1 | ATH)
    {
        int tot = 4 * 128 * 160 + 4 * 128 * 128 + 128 * 128;
        k_prep_weights<<<dim3((tot + 255) / 256), b256, 0, stream>>>(W0, W1, Wmu, Wlv, AT0, AT1, ATH);
    }

    // K1: layer-0 pair-GEMM tiles + tail atomics
    int G64 = (N + 63) / 64;
    int total = 2 * G64;
    int EPC = (E + total - 1) / total;
    k_mega<<<dim3(total), b256, 0, stream>>>(src, dst, ew, deg, cnt, rank, x, pe, AT0,
                                             (unsigned short*)B1, (unsigned short*)B2,
                                             (unsigned short*)B3, (unsigned short*)B4,
                                             N, E, EPC);

    int nb = (N + 1023) / 1024;
    k_dis_blocksum<<<dim3(nb), dim3(1024), 0, stream>>>(deg, cnt, bsum, N);
    k_scan_bsum<<<dim3(1), dim3(128), 0, stream>>>(bsum, nb);
    k_scan<<<dim3(nb), dim3(1024), 0, stream>>>(cnt, bsum, rowp, N);
    k_build_csr<<<dim3((E + 1023) / 1024), b256, 0, stream>>>(src, dst, ew, deg, rowp, rank, pack, E);

    dim3 gp((N + 3) / 4);
    const long long* packll = (const long long*)pack;
    uint4* B1v = (uint4*)B1; uint4* B2v = (uint4*)B2; uint4* B3v = (uint4*)B3;
    uint4* B4v = (uint4*)B4; uint4* B5v = (uint4*)B5;

    // layer 0 (Horner): B1=Z3 B2=Z2 B3=Z1 B4=Z0 (from K1)
    k_prop<0><<<gp, b256, 0, stream>>>(B1v, B2v, B5v, nullptr, rowp, packll, N, E);   // B5 = Z2 + P Z3
    k_prop<0><<<gp, b256, 0, stream>>>(B5v, B3v, B1v, nullptr, rowp, packll, N, E);   // B1 = Z1 + P B5
    k_prop<1><<<gp, b256, 0, stream>>>(B1v, B4v, B2v, b0, rowp, packll, N, E);        // B2 = h1

    // layer 1 (powers form): U1 = P h1, U2 = P U1, U3 = P U2
    k_prop<2><<<gp, b256, 0, stream>>>(B2v, nullptr, B3v, nullptr, rowp, packll, N, E);  // B3 = U1
    k_prop<2><<<gp, b256, 0, stream>>>(B3v, nullptr, B4v, nullptr, rowp, packll, N, E);  // B4 = U2
    k_prop<2><<<gp, b256, 0, stream>>>(B4v, nullptr, B5v, nullptr, rowp, packll, N, E);  // B5 = U3

    // fused: h2 = relu([h1|U1|U2|U3]@AT1 + b1) -> heads -> d_out
    k_gemm_l1_heads<<<dim3(G64), b256, 0, stream>>>((const unsigned short*)B2, (const unsigned short*)B3,
                                                    (const unsigned short*)B4, (const unsigned short*)B5,
                                                    AT1, ATH, b1, bmu, blv, (float*)d_out, N);
}